// Round 1
// baseline (1055.111 us; speedup 1.0000x reference)
//
#include <hip/hip_runtime.h>

#define BN_INV  0.99999500003749981f
#define QSCALE  0.21320071635561041f   // 22^-0.5

// ---- ws layout (float offsets). Total 5211272 floats (~20.9 MB). ----
#define OFF_WCAT 0         // 88*264  folded w1|w2a|w3a, [i][j] layout
#define OFF_BCAT 23232     // 264
#define OFF_W2B  23496     // 3*88*88 [t][i][o]
#define OFF_W3B  46728
#define OFF_W3C  69960     // 5*88*88
#define OFF_WMP  108680    // 264*88  [c][o]
#define OFF_WQKV 131912    // 88*264  [h][ q|k|v ]
#define OFF_WOUT 155144    // 112*88  [j][o]
#define OFF_XCAT 165000    // 8192*264 (t1|t2a|t3a) -- dead after mpk
#define OFF_Q    165000    // 16*2048*22  (overlays XCAT)
#define OFF_K    885896
#define OFF_CD   1606792   // 16*2048*14
#define OFF_X2   2327688   // 8192*88 -- dead after mpk
#define OFF_XO   2327688   // 8192*112 (overlays X2 + part of T3B)
#define OFF_T3B  3048584   // 8192*88
#define OFF_X3   3769480   // 8192*88
#define OFF_MP   4490376   // 8192*88

__constant__ float c_dlo[8] = {-0.010597401784997278f, 0.032883011666982945f,
    0.030841381835986965f, -0.18703481171888114f, -0.02798376941698385f,
    0.6308807679295904f, 0.7148465705525415f, 0.23037781330885523f};
__constant__ float c_dhi[8] = {-0.23037781330885523f, 0.7148465705525415f,
    -0.6308807679295904f, -0.02798376941698385f, 0.18703481171888114f,
    0.030841381835986965f, -0.032883011666982945f, -0.010597401784997278f};

// ---------------- weight prep: fold BN, transpose for coalesced reads ----
__global__ __launch_bounds__(256) void prepk(
    const float* __restrict__ w1, const float* __restrict__ w2a, const float* __restrict__ w2b,
    const float* __restrict__ w3a, const float* __restrict__ w3b, const float* __restrict__ w3c,
    const float* __restrict__ g1, const float* __restrict__ g2a, const float* __restrict__ g2b,
    const float* __restrict__ g3a, const float* __restrict__ g3b, const float* __restrict__ g3c,
    const float* __restrict__ b1, const float* __restrict__ b2a, const float* __restrict__ b3a,
    const float* __restrict__ Wmp, const float* __restrict__ Wq, const float* __restrict__ Wk,
    const float* __restrict__ Wv, const float* __restrict__ Wout, float* __restrict__ ws)
{
    int r = blockIdx.x * 256 + threadIdx.x;
    if (r < 88*264) {                       // Wcat_t [i][j]
        int i = r / 264, j = r % 264; float v;
        if (j < 88)       v = w1 [j*88+i]       * g1 [j];
        else if (j < 176) v = w2a[(j-88)*88+i]  * g2a[j-88];
        else              v = w3a[(j-176)*88+i] * g3a[j-176];
        ws[OFF_WCAT + r] = v * BN_INV; return;
    }
    r -= 88*264;
    if (r < 264) {
        ws[OFF_BCAT + r] = (r < 88) ? b1[r] : (r < 176 ? b2a[r-88] : b3a[r-176]);
        return;
    }
    r -= 264;
    if (r < 3*88*88) {                      // W2b [t][i][o]
        int t = r/7744, q = r%7744, i = q/88, o = q%88;
        ws[OFF_W2B + r] = w2b[o*264 + i*3 + t] * g2b[o] * BN_INV; return;
    }
    r -= 3*88*88;
    if (r < 3*88*88) {
        int t = r/7744, q = r%7744, i = q/88, o = q%88;
        ws[OFF_W3B + r] = w3b[o*264 + i*3 + t] * g3b[o] * BN_INV; return;
    }
    r -= 3*88*88;
    if (r < 5*88*88) {                      // W3c [t][i][o]
        int t = r/7744, q = r%7744, i = q/88, o = q%88;
        ws[OFF_W3C + r] = w3c[o*440 + i*5 + t] * g3c[o] * BN_INV; return;
    }
    r -= 5*88*88;
    if (r < 264*88) {                       // Wmp_t [c][o]
        int c = r/88, o = r%88;
        ws[OFF_WMP + r] = Wmp[o*264 + c]; return;
    }
    r -= 264*88;
    if (r < 88*264) {                       // Wqkv_t [h][j]; q-scale folded
        int h = r/264, j = r%264; float v;
        if (j < 88)       v = Wq[j*88+h] * QSCALE;
        else if (j < 176) v = Wk[(j-88)*88+h];
        else              v = Wv[(j-176)*88+h];
        ws[OFF_WQKV + r] = v; return;
    }
    r -= 88*264;
    if (r < 112*88) {                       // Wout_t [j][o]
        int j = r/88, o = r%88;
        ws[OFF_WOUT + r] = Wout[o*112 + j]; return;
    }
}

// ---------------- fused 1x1 convs: x -> [t1|t2a|t3a] with bn+relu ---------
__global__ __launch_bounds__(256) void conv1k(const float* __restrict__ x, float* __restrict__ ws)
{
    __shared__ float xr[704];               // 8 rows x 88
    const float* Wc = ws + OFF_WCAT;
    const float* bc = ws + OFF_BCAT;
    float* out = ws + OFF_XCAT;
    int p0 = blockIdx.x * 8, tid = threadIdx.x;
    for (int e = tid; e < 704; e += 256) xr[e] = x[p0*88 + e];
    __syncthreads();
    for (int j = tid; j < 264; j += 256) {
        float bb = bc[j];
        float acc[8];
        #pragma unroll
        for (int p = 0; p < 8; p++) acc[p] = bb;
        for (int i = 0; i < 88; i++) {
            float w = Wc[i*264 + j];
            #pragma unroll
            for (int p = 0; p < 8; p++) acc[p] = fmaf(xr[p*88+i], w, acc[p]);
        }
        #pragma unroll
        for (int p = 0; p < 8; p++) out[(p0+p)*264 + j] = fmaxf(acc[p], 0.f);
    }
}

// ---------------- k=3 convs (t2a->x2, t3a->t3b), zero-padded per batch ----
__global__ __launch_bounds__(128) void conv3k(float* __restrict__ ws,
    const float* __restrict__ b2b, const float* __restrict__ b3b)
{
    __shared__ float xr[880];               // 10 rows x 88
    int which = blockIdx.y;
    const float* W   = ws + (which == 0 ? OFF_W2B : OFF_W3B);
    const float* src = ws + OFF_XCAT + (which == 0 ? 88 : 176);
    const float* bias = which == 0 ? b2b : b3b;
    float* dst = ws + (which == 0 ? OFF_X2 : OFF_T3B);
    int p0 = blockIdx.x * 8, tid = threadIdx.x;
    int bs = (p0 >> 11) << 11, be = bs + 2048;
    for (int e = tid; e < 880; e += 128) {
        int p = e / 88, i = e % 88, row = p0 - 1 + p;
        xr[e] = (row >= bs && row < be) ? src[row*264 + i] : 0.f;
    }
    __syncthreads();
    if (tid < 88) {
        int j = tid; float bb = bias[j];
        float acc[8];
        #pragma unroll
        for (int p = 0; p < 8; p++) acc[p] = bb;
        for (int t = 0; t < 3; t++)
            for (int i = 0; i < 88; i++) {
                float w = W[(t*88+i)*88 + j];
                #pragma unroll
                for (int p = 0; p < 8; p++) acc[p] = fmaf(xr[(p+t)*88+i], w, acc[p]);
            }
        #pragma unroll
        for (int p = 0; p < 8; p++) dst[(p0+p)*88 + j] = fmaxf(acc[p], 0.f);
    }
}

// ---------------- k=5 conv (t3b->x3) -------------------------------------
__global__ __launch_bounds__(128) void conv5k(float* __restrict__ ws, const float* __restrict__ b3c)
{
    __shared__ float xr[1056];              // 12 rows x 88
    const float* W = ws + OFF_W3C;
    const float* src = ws + OFF_T3B;
    float* dst = ws + OFF_X3;
    int p0 = blockIdx.x * 8, tid = threadIdx.x;
    int bs = (p0 >> 11) << 11, be = bs + 2048;
    for (int e = tid; e < 1056; e += 128) {
        int p = e / 88, i = e % 88, row = p0 - 2 + p;
        xr[e] = (row >= bs && row < be) ? src[row*88 + i] : 0.f;
    }
    __syncthreads();
    if (tid < 88) {
        int j = tid; float bb = b3c[j];
        float acc[8];
        #pragma unroll
        for (int p = 0; p < 8; p++) acc[p] = bb;
        for (int t = 0; t < 5; t++)
            for (int i = 0; i < 88; i++) {
                float w = W[(t*88+i)*88 + j];
                #pragma unroll
                for (int p = 0; p < 8; p++) acc[p] = fmaf(xr[(p+t)*88+i], w, acc[p]);
            }
        #pragma unroll
        for (int p = 0; p < 8; p++) dst[(p0+p)*88 + j] = fmaxf(acc[p], 0.f);
    }
}

// ---------------- mp = cat(x1,x2,x3)@Wmp^T + bmp + x ----------------------
__global__ __launch_bounds__(128) void mpk(const float* __restrict__ x,
    const float* __restrict__ bmp, float* __restrict__ ws)
{
    __shared__ float r1[704], r2[704], r3[704];
    const float* Wm = ws + OFF_WMP;
    int p0 = blockIdx.x * 8, tid = threadIdx.x;
    for (int e = tid; e < 704; e += 128) {
        int p = e / 88, i = e % 88;
        r1[e] = ws[OFF_XCAT + (p0+p)*264 + i];
        r2[e] = ws[OFF_X2 + p0*88 + e];
        r3[e] = ws[OFF_X3 + p0*88 + e];
    }
    __syncthreads();
    if (tid < 88) {
        int o = tid; float bb = bmp[o];
        float acc[8];
        #pragma unroll
        for (int p = 0; p < 8; p++) acc[p] = bb;
        for (int c = 0; c < 88; c++) {
            float w = Wm[c*88 + o];
            #pragma unroll
            for (int p = 0; p < 8; p++) acc[p] = fmaf(r1[p*88+c], w, acc[p]);
        }
        for (int c = 0; c < 88; c++) {
            float w = Wm[(88+c)*88 + o];
            #pragma unroll
            for (int p = 0; p < 8; p++) acc[p] = fmaf(r2[p*88+c], w, acc[p]);
        }
        for (int c = 0; c < 88; c++) {
            float w = Wm[(176+c)*88 + o];
            #pragma unroll
            for (int p = 0; p < 8; p++) acc[p] = fmaf(r3[p*88+c], w, acc[p]);
        }
        #pragma unroll
        for (int p = 0; p < 8; p++)
            ws[OFF_MP + (p0+p)*88 + o] = acc[p] + x[(p0+p)*88 + o];
    }
}

// ---------------- qkv projection + DWT(v) ---------------------------------
__global__ __launch_bounds__(128) void qkvk(float* __restrict__ ws)
{
    __shared__ float mr[704];
    __shared__ float vr[704];
    const float* Wqkv = ws + OFF_WQKV;
    int p0 = blockIdx.x * 8, tid = threadIdx.x;
    for (int e = tid; e < 704; e += 128) mr[e] = ws[OFF_MP + p0*88 + e];
    __syncthreads();
    for (int j = tid; j < 264; j += 128) {
        float acc[8] = {0,0,0,0,0,0,0,0};
        for (int hh = 0; hh < 88; hh++) {
            float w = Wqkv[hh*264 + j];
            #pragma unroll
            for (int p = 0; p < 8; p++) acc[p] = fmaf(mr[p*88+hh], w, acc[p]);
        }
        if (j < 176) {
            int isq = j < 88 ? 1 : 0;
            int jo = isq ? j : j - 88;
            int h = jo / 22, d = jo % 22;
            float* dst = ws + (isq ? OFF_Q : OFF_K) + h*2048*22 + d;
            #pragma unroll
            for (int p = 0; p < 8; p++) {
                int pos = p0 + p, b = pos >> 11, s = pos & 2047;
                dst[(size_t)b*4*2048*22 + s*22] = acc[p];
            }
        } else {
            #pragma unroll
            for (int p = 0; p < 8; p++) vr[p*88 + (j-176)] = acc[p];
        }
    }
    __syncthreads();
    // DWT: 8 pos x 4 heads x 14 taps
    for (int e = tid; e < 448; e += 128) {
        int p = e / 56, rr = e % 56, h = rr / 14, jj = rr % 14;
        const float* v = &vr[p*88 + h*22];
        float ca = 0.f, cd = 0.f;
        #pragma unroll
        for (int t = 0; t < 8; t++) {
            int pp = 1 + 2*jj + t;
            int oi = pp < 7 ? 6 - pp : (pp < 29 ? pp - 7 : 50 - pp);
            float vv = v[oi];
            ca = fmaf(vv, c_dlo[7-t], ca);
            cd = fmaf(vv, c_dhi[7-t], cd);
        }
        int pos = p0 + p, b = pos >> 11, s = pos & 2047;
        ws[OFF_CD + ((b*4+h)*2048 + s)*14 + jj] = cd;
        // replicate reference's transposeless reshape of cA:
        int hs = h*2048 + s, s2 = hs >> 2, qd = hs & 3;
        ws[OFF_XO + (b*2048 + s2)*112 + 56 + qd*14 + jj] = ca;
    }
}

// ---------------- flash attention: softmax(QK^T) @ cD, relu, -> XO --------
__global__ __launch_bounds__(128) void attnk(float* __restrict__ ws)
{
    __shared__ float4 kt4[64*6];            // 64 keys x 24 floats (padded)
    __shared__ float4 cd4[64*4];            // 64 keys x 16 floats (padded)
    float* kt = (float*)kt4;
    float* cdt = (float*)cd4;
    int bh = blockIdx.y;                    // = b*4 + h
    int tid = threadIdx.x;
    int row = blockIdx.x * 128 + tid;       // q row in [0,2048)
    const float* Qb = ws + OFF_Q  + (size_t)bh*2048*22;
    const float* Kb = ws + OFF_K  + (size_t)bh*2048*22;
    const float* Db = ws + OFF_CD + (size_t)bh*2048*14;

    float q[24];
    #pragma unroll
    for (int d = 0; d < 22; d++) q[d] = Qb[row*22 + d];
    q[22] = 0.f; q[23] = 0.f;

    float m = -1e30f, l = 0.f;
    float4 acc4[4];
    #pragma unroll
    for (int f = 0; f < 4; f++) acc4[f] = make_float4(0.f, 0.f, 0.f, 0.f);

    for (int tile = 0; tile < 32; tile++) {
        __syncthreads();
        for (int e = tid; e < 1536; e += 128) {
            int kk = e / 24, d = e % 24;
            kt[e] = d < 22 ? Kb[(tile*64 + kk)*22 + d] : 0.f;
        }
        for (int e = tid; e < 1024; e += 128) {
            int kk = e / 16, d = e % 16;
            cdt[e] = d < 14 ? Db[(tile*64 + kk)*14 + d] : 0.f;
        }
        __syncthreads();
        #pragma unroll
        for (int half = 0; half < 2; half++) {
            float sc[32];
            #pragma unroll
            for (int kk = 0; kk < 32; kk++) {
                const float4* kr = &kt4[(half*32 + kk)*6];
                float s = 0.f;
                #pragma unroll
                for (int f = 0; f < 6; f++) {
                    float4 kv = kr[f];
                    s = fmaf(q[4*f+0], kv.x, s);
                    s = fmaf(q[4*f+1], kv.y, s);
                    s = fmaf(q[4*f+2], kv.z, s);
                    s = fmaf(q[4*f+3], kv.w, s);
                }
                sc[kk] = s;
            }
            float tm = m;
            #pragma unroll
            for (int kk = 0; kk < 32; kk++) tm = fmaxf(tm, sc[kk]);
            float corr = __expf(m - tm);
            m = tm; l *= corr;
            #pragma unroll
            for (int f = 0; f < 4; f++) {
                acc4[f].x *= corr; acc4[f].y *= corr;
                acc4[f].z *= corr; acc4[f].w *= corr;
            }
            #pragma unroll
            for (int kk = 0; kk < 32; kk++) {
                float e = __expf(sc[kk] - m);
                l += e;
                const float4* cr = &cd4[(half*32 + kk)*4];
                #pragma unroll
                for (int f = 0; f < 4; f++) {
                    float4 cv = cr[f];
                    acc4[f].x = fmaf(e, cv.x, acc4[f].x);
                    acc4[f].y = fmaf(e, cv.y, acc4[f].y);
                    acc4[f].z = fmaf(e, cv.z, acc4[f].z);
                    acc4[f].w = fmaf(e, cv.w, acc4[f].w);
                }
            }
        }
    }
    float inv = 1.f / l;
    const float* acc = (const float*)acc4;
    int b = bh >> 2, h = bh & 3;
    float* xo = ws + OFF_XO + ((size_t)b*2048 + row)*112 + h*14;
    #pragma unroll
    for (int j = 0; j < 14; j++) xo[j] = fmaxf(acc[j]*inv, 0.f);
}

// ---------------- out = mp + concat(xo,cA) @ Wout^T + bout ----------------
__global__ __launch_bounds__(128) void finalk(const float* __restrict__ bout,
    float* __restrict__ ws, float* __restrict__ out)
{
    __shared__ float xr[896];               // 8 rows x 112
    const float* Wo = ws + OFF_WOUT;
    int p0 = blockIdx.x * 8, tid = threadIdx.x;
    for (int e = tid; e < 896; e += 128) xr[e] = ws[OFF_XO + p0*112 + e];
    __syncthreads();
    if (tid < 88) {
        int o = tid; float bb = bout[o];
        float acc[8];
        #pragma unroll
        for (int p = 0; p < 8; p++) acc[p] = bb;
        for (int i = 0; i < 112; i++) {
            float w = Wo[i*88 + o];
            #pragma unroll
            for (int p = 0; p < 8; p++) acc[p] = fmaf(xr[p*112+i], w, acc[p]);
        }
        #pragma unroll
        for (int p = 0; p < 8; p++)
            out[(p0+p)*88 + o] = acc[p] + ws[OFF_MP + (p0+p)*88 + o];
    }
}

extern "C" void kernel_launch(void* const* d_in, const int* in_sizes, int n_in,
                              void* d_out, int out_size, void* d_ws, size_t ws_size,
                              hipStream_t stream) {
    const float* x    = (const float*)d_in[0];
    const float* w1   = (const float*)d_in[1];
    const float* w2a  = (const float*)d_in[2];
    const float* w2b  = (const float*)d_in[3];
    const float* w3a  = (const float*)d_in[4];
    const float* w3b  = (const float*)d_in[5];
    const float* w3c  = (const float*)d_in[6];
    const float* g1   = (const float*)d_in[7];
    const float* g2a  = (const float*)d_in[8];
    const float* g2b  = (const float*)d_in[9];
    const float* g3a  = (const float*)d_in[10];
    const float* g3b  = (const float*)d_in[11];
    const float* g3c  = (const float*)d_in[12];
    const float* b1   = (const float*)d_in[13];
    const float* b2a  = (const float*)d_in[14];
    const float* b2b  = (const float*)d_in[15];
    const float* b3a  = (const float*)d_in[16];
    const float* b3b  = (const float*)d_in[17];
    const float* b3c  = (const float*)d_in[18];
    const float* Wmp  = (const float*)d_in[19];
    const float* bmp  = (const float*)d_in[20];
    const float* Wq   = (const float*)d_in[21];
    const float* Wk   = (const float*)d_in[22];
    const float* Wv   = (const float*)d_in[23];
    const float* Wout = (const float*)d_in[24];
    const float* bout = (const float*)d_in[25];
    float* ws = (float*)d_ws;
    float* out = (float*)d_out;

    prepk<<<645, 256, 0, stream>>>(w1, w2a, w2b, w3a, w3b, w3c,
                                   g1, g2a, g2b, g3a, g3b, g3c,
                                   b1, b2a, b3a, Wmp, Wq, Wk, Wv, Wout, ws);
    conv1k<<<1024, 256, 0, stream>>>(x, ws);
    conv3k<<<dim3(1024, 2), 128, 0, stream>>>(ws, b2b, b3b);
    conv5k<<<1024, 128, 0, stream>>>(ws, b3c);
    mpk<<<1024, 128, 0, stream>>>(x, bmp, ws);
    qkvk<<<1024, 128, 0, stream>>>(ws);
    attnk<<<dim3(16, 16), 128, 0, stream>>>(ws);
    finalk<<<1024, 128, 0, stream>>>(bout, ws, out);
}

// Round 2
// 368.944 us; speedup vs baseline: 2.8598x; 2.8598x over previous
//
#include <hip/hip_runtime.h>

#define BN_INV  0.99999500003749981f
#define QSCALE  0.21320071635561041f   // 22^-0.5

// ---- ws layout (float offsets). ----
#define OFF_WCAT 0         // 88*264  folded w1|w2a|w3a, [i][j] layout
#define OFF_BCAT 23232     // 264
#define OFF_W2B  23496     // 3*88*88 [t][i][o]
#define OFF_W3B  46728
#define OFF_W3C  69960     // 5*88*88
#define OFF_WMP  108680    // 264*88  [c][o]
#define OFF_WQKV 131912    // 88*264  [h][ q|k|v ]
#define OFF_WOUT 155144    // 112*88  [j][o]
#define OFF_XCAT 165000    // 8192*264 (t1|t2a|t3a) -- dead after mpk
#define OFF_Q    165000    // 16*2048*24 (padded to 24) overlays XCAT
#define OFF_K    951432    // 16*2048*24
#define OFF_CD   1737864   // 16*2048*16 (padded to 16); ends 2262152 < 2327688
#define OFF_X2   2327688   // 8192*88 -- dead after mpk
#define OFF_XO   2327688   // 8192*112 (overlays X2 + part of T3B)
#define OFF_T3B  3048584   // 8192*88
#define OFF_X3   3769480   // 8192*88
#define OFF_MP   4490376   // 8192*88

__constant__ float c_dlo[8] = {-0.010597401784997278f, 0.032883011666982945f,
    0.030841381835986965f, -0.18703481171888114f, -0.02798376941698385f,
    0.6308807679295904f, 0.7148465705525415f, 0.23037781330885523f};
__constant__ float c_dhi[8] = {-0.23037781330885523f, 0.7148465705525415f,
    -0.6308807679295904f, -0.02798376941698385f, 0.18703481171888114f,
    0.030841381835986965f, -0.032883011666982945f, -0.010597401784997278f};

// ---------------- weight prep: fold BN, transpose for coalesced reads ----
__global__ __launch_bounds__(256) void prepk(
    const float* __restrict__ w1, const float* __restrict__ w2a, const float* __restrict__ w2b,
    const float* __restrict__ w3a, const float* __restrict__ w3b, const float* __restrict__ w3c,
    const float* __restrict__ g1, const float* __restrict__ g2a, const float* __restrict__ g2b,
    const float* __restrict__ g3a, const float* __restrict__ g3b, const float* __restrict__ g3c,
    const float* __restrict__ b1, const float* __restrict__ b2a, const float* __restrict__ b3a,
    const float* __restrict__ Wmp, const float* __restrict__ Wq, const float* __restrict__ Wk,
    const float* __restrict__ Wv, const float* __restrict__ Wout, float* __restrict__ ws)
{
    int r = blockIdx.x * 256 + threadIdx.x;
    if (r < 88*264) {                       // Wcat_t [i][j]
        int i = r / 264, j = r % 264; float v;
        if (j < 88)       v = w1 [j*88+i]       * g1 [j];
        else if (j < 176) v = w2a[(j-88)*88+i]  * g2a[j-88];
        else              v = w3a[(j-176)*88+i] * g3a[j-176];
        ws[OFF_WCAT + r] = v * BN_INV; return;
    }
    r -= 88*264;
    if (r < 264) {
        ws[OFF_BCAT + r] = (r < 88) ? b1[r] : (r < 176 ? b2a[r-88] : b3a[r-176]);
        return;
    }
    r -= 264;
    if (r < 3*88*88) {                      // W2b [t][i][o]
        int t = r/7744, q = r%7744, i = q/88, o = q%88;
        ws[OFF_W2B + r] = w2b[o*264 + i*3 + t] * g2b[o] * BN_INV; return;
    }
    r -= 3*88*88;
    if (r < 3*88*88) {
        int t = r/7744, q = r%7744, i = q/88, o = q%88;
        ws[OFF_W3B + r] = w3b[o*264 + i*3 + t] * g3b[o] * BN_INV; return;
    }
    r -= 3*88*88;
    if (r < 5*88*88) {                      // W3c [t][i][o]
        int t = r/7744, q = r%7744, i = q/88, o = q%88;
        ws[OFF_W3C + r] = w3c[o*440 + i*5 + t] * g3c[o] * BN_INV; return;
    }
    r -= 5*88*88;
    if (r < 264*88) {                       // Wmp_t [c][o]
        int c = r/88, o = r%88;
        ws[OFF_WMP + r] = Wmp[o*264 + c]; return;
    }
    r -= 264*88;
    if (r < 88*264) {                       // Wqkv_t [h][j]; q-scale folded
        int h = r/264, j = r%264; float v;
        if (j < 88)       v = Wq[j*88+h] * QSCALE;
        else if (j < 176) v = Wk[(j-88)*88+h];
        else              v = Wv[(j-176)*88+h];
        ws[OFF_WQKV + r] = v; return;
    }
    r -= 88*264;
    if (r < 112*88) {                       // Wout_t [j][o]
        int j = r/88, o = r%88;
        ws[OFF_WOUT + r] = Wout[o*112 + j]; return;
    }
}

// ---------------- fused 1x1 convs: x -> [t1|t2a|t3a] with bn+relu ---------
__global__ __launch_bounds__(256) void conv1k(const float* __restrict__ x, float* __restrict__ ws)
{
    __shared__ float xr[704];               // 8 rows x 88
    const float* Wc = ws + OFF_WCAT;
    const float* bc = ws + OFF_BCAT;
    float* out = ws + OFF_XCAT;
    int p0 = blockIdx.x * 8, tid = threadIdx.x;
    for (int e = tid; e < 704; e += 256) xr[e] = x[p0*88 + e];
    __syncthreads();
    for (int j = tid; j < 264; j += 256) {
        float bb = bc[j];
        float acc[8];
        #pragma unroll
        for (int p = 0; p < 8; p++) acc[p] = bb;
        for (int i = 0; i < 88; i++) {
            float w = Wc[i*264 + j];
            #pragma unroll
            for (int p = 0; p < 8; p++) acc[p] = fmaf(xr[p*88+i], w, acc[p]);
        }
        #pragma unroll
        for (int p = 0; p < 8; p++) out[(p0+p)*264 + j] = fmaxf(acc[p], 0.f);
    }
}

// ---------------- k=3 convs (t2a->x2, t3a->t3b), zero-padded per batch ----
__global__ __launch_bounds__(128) void conv3k(float* __restrict__ ws,
    const float* __restrict__ b2b, const float* __restrict__ b3b)
{
    __shared__ float xr[880];               // 10 rows x 88
    int which = blockIdx.y;
    const float* W   = ws + (which == 0 ? OFF_W2B : OFF_W3B);
    const float* src = ws + OFF_XCAT + (which == 0 ? 88 : 176);
    const float* bias = which == 0 ? b2b : b3b;
    float* dst = ws + (which == 0 ? OFF_X2 : OFF_T3B);
    int p0 = blockIdx.x * 8, tid = threadIdx.x;
    int bs = (p0 >> 11) << 11, be = bs + 2048;
    for (int e = tid; e < 880; e += 128) {
        int p = e / 88, i = e % 88, row = p0 - 1 + p;
        xr[e] = (row >= bs && row < be) ? src[row*264 + i] : 0.f;
    }
    __syncthreads();
    if (tid < 88) {
        int j = tid; float bb = bias[j];
        float acc[8];
        #pragma unroll
        for (int p = 0; p < 8; p++) acc[p] = bb;
        for (int t = 0; t < 3; t++)
            for (int i = 0; i < 88; i++) {
                float w = W[(t*88+i)*88 + j];
                #pragma unroll
                for (int p = 0; p < 8; p++) acc[p] = fmaf(xr[(p+t)*88+i], w, acc[p]);
            }
        #pragma unroll
        for (int p = 0; p < 8; p++) dst[(p0+p)*88 + j] = fmaxf(acc[p], 0.f);
    }
}

// ---------------- k=5 conv (t3b->x3) -------------------------------------
__global__ __launch_bounds__(128) void conv5k(float* __restrict__ ws, const float* __restrict__ b3c)
{
    __shared__ float xr[1056];              // 12 rows x 88
    const float* W = ws + OFF_W3C;
    const float* src = ws + OFF_T3B;
    float* dst = ws + OFF_X3;
    int p0 = blockIdx.x * 8, tid = threadIdx.x;
    int bs = (p0 >> 11) << 11, be = bs + 2048;
    for (int e = tid; e < 1056; e += 128) {
        int p = e / 88, i = e % 88, row = p0 - 2 + p;
        xr[e] = (row >= bs && row < be) ? src[row*88 + i] : 0.f;
    }
    __syncthreads();
    if (tid < 88) {
        int j = tid; float bb = b3c[j];
        float acc[8];
        #pragma unroll
        for (int p = 0; p < 8; p++) acc[p] = bb;
        for (int t = 0; t < 5; t++)
            for (int i = 0; i < 88; i++) {
                float w = W[(t*88+i)*88 + j];
                #pragma unroll
                for (int p = 0; p < 8; p++) acc[p] = fmaf(xr[(p+t)*88+i], w, acc[p]);
            }
        #pragma unroll
        for (int p = 0; p < 8; p++) dst[(p0+p)*88 + j] = fmaxf(acc[p], 0.f);
    }
}

// ---------------- mp = cat(x1,x2,x3)@Wmp^T + bmp + x ----------------------
__global__ __launch_bounds__(128) void mpk(const float* __restrict__ x,
    const float* __restrict__ bmp, float* __restrict__ ws)
{
    __shared__ float r1[704], r2[704], r3[704];
    const float* Wm = ws + OFF_WMP;
    int p0 = blockIdx.x * 8, tid = threadIdx.x;
    for (int e = tid; e < 704; e += 128) {
        int p = e / 88, i = e % 88;
        r1[e] = ws[OFF_XCAT + (p0+p)*264 + i];
        r2[e] = ws[OFF_X2 + p0*88 + e];
        r3[e] = ws[OFF_X3 + p0*88 + e];
    }
    __syncthreads();
    if (tid < 88) {
        int o = tid; float bb = bmp[o];
        float acc[8];
        #pragma unroll
        for (int p = 0; p < 8; p++) acc[p] = bb;
        for (int c = 0; c < 88; c++) {
            float w = Wm[c*88 + o];
            #pragma unroll
            for (int p = 0; p < 8; p++) acc[p] = fmaf(r1[p*88+c], w, acc[p]);
        }
        for (int c = 0; c < 88; c++) {
            float w = Wm[(88+c)*88 + o];
            #pragma unroll
            for (int p = 0; p < 8; p++) acc[p] = fmaf(r2[p*88+c], w, acc[p]);
        }
        for (int c = 0; c < 88; c++) {
            float w = Wm[(176+c)*88 + o];
            #pragma unroll
            for (int p = 0; p < 8; p++) acc[p] = fmaf(r3[p*88+c], w, acc[p]);
        }
        #pragma unroll
        for (int p = 0; p < 8; p++)
            ws[OFF_MP + (p0+p)*88 + o] = acc[p] + x[(p0+p)*88 + o];
    }
}

// ---------------- qkv projection + DWT(v) ---------------------------------
// Q,K padded to 24 floats/row (zeros), cD padded to 16 floats/row (zeros).
__global__ __launch_bounds__(128) void qkvk(float* __restrict__ ws)
{
    __shared__ float mr[704];
    __shared__ float vr[704];
    const float* Wqkv = ws + OFF_WQKV;
    int p0 = blockIdx.x * 8, tid = threadIdx.x;
    for (int e = tid; e < 704; e += 128) mr[e] = ws[OFF_MP + p0*88 + e];
    __syncthreads();
    for (int j = tid; j < 264; j += 128) {
        float acc[8] = {0,0,0,0,0,0,0,0};
        for (int hh = 0; hh < 88; hh++) {
            float w = Wqkv[hh*264 + j];
            #pragma unroll
            for (int p = 0; p < 8; p++) acc[p] = fmaf(mr[p*88+hh], w, acc[p]);
        }
        if (j < 176) {
            int isq = j < 88 ? 1 : 0;
            int jo = isq ? j : j - 88;
            int h = jo / 22, d = jo % 22;
            float* dst = ws + (isq ? OFF_Q : OFF_K) + d;
            #pragma unroll
            for (int p = 0; p < 8; p++) {
                int pos = p0 + p, b = pos >> 11, s = pos & 2047;
                dst[((size_t)(b*4 + h)*2048 + s)*24] = acc[p];
            }
        } else {
            #pragma unroll
            for (int p = 0; p < 8; p++) vr[p*88 + (j-176)] = acc[p];
        }
    }
    // zero the pads of Q/K (d=22,23)
    if (tid < 128) {
        int e = tid;
        int p = e >> 4, h = (e >> 2) & 3, w = (e >> 1) & 1, d = 22 + (e & 1);
        int pos = p0 + p, b = pos >> 11, s = pos & 2047;
        ws[(w ? OFF_K : OFF_Q) + ((size_t)(b*4 + h)*2048 + s)*24 + d] = 0.f;
    }
    // zero the pads of cD (d=14,15)
    for (int e = tid; e < 64; e += 128) {
        int p = e >> 3, h = (e >> 1) & 3, d = 14 + (e & 1);
        int pos = p0 + p, b = pos >> 11, s = pos & 2047;
        ws[OFF_CD + ((size_t)(b*4 + h)*2048 + s)*16 + d] = 0.f;
    }
    __syncthreads();
    // DWT: 8 pos x 4 heads x 14 taps
    for (int e = tid; e < 448; e += 128) {
        int p = e / 56, rr = e % 56, h = rr / 14, jj = rr % 14;
        const float* v = &vr[p*88 + h*22];
        float ca = 0.f, cd = 0.f;
        #pragma unroll
        for (int t = 0; t < 8; t++) {
            int pp = 1 + 2*jj + t;
            int oi = pp < 7 ? 6 - pp : (pp < 29 ? pp - 7 : 50 - pp);
            float vv = v[oi];
            ca = fmaf(vv, c_dlo[7-t], ca);
            cd = fmaf(vv, c_dhi[7-t], cd);
        }
        int pos = p0 + p, b = pos >> 11, s = pos & 2047;
        ws[OFF_CD + ((size_t)(b*4+h)*2048 + s)*16 + jj] = cd;
        // replicate reference's transposeless reshape of cA:
        int hs = h*2048 + s, s2 = hs >> 2, qd = hs & 3;
        ws[OFF_XO + ((size_t)b*2048 + s2)*112 + 56 + qd*14 + jj] = ca;
    }
}

// ---------------- flash attention, in-block split-K ------------------------
// 512 threads = 8 waves. Wave sp handles keys [sp*256, sp*256+256) for the
// block's 64 q-rows (one row per lane). Partials (m,l,acc[14]) merged in LDS.
__global__ __launch_bounds__(512, 4) void attnk(float* __restrict__ ws)
{
    __shared__ float kst[8*16*24];          // per split: 16 keys x 24
    __shared__ float cdst[8*16*16];         // per split: 16 keys x 16
    __shared__ float part[512*16];          // [sp][row][16]: m,l,acc14
    int tid = threadIdx.x;
    int sp = tid >> 6, r = tid & 63;
    int bh = blockIdx.y;
    int row = blockIdx.x * 64 + r;
    const float* Qb = ws + OFF_Q  + (size_t)bh*2048*24;
    const float* Kb = ws + OFF_K  + (size_t)bh*2048*24;
    const float* Db = ws + OFF_CD + (size_t)bh*2048*16;

    float4 q4[6];
    const float4* qp = (const float4*)&Qb[row*24];
    #pragma unroll
    for (int f = 0; f < 6; f++) q4[f] = qp[f];

    float m = -1e30f, l = 0.f;
    float4 acc4[4];
    #pragma unroll
    for (int f = 0; f < 4; f++) acc4[f] = make_float4(0.f, 0.f, 0.f, 0.f);

    const float4* kst4 = (const float4*)kst;
    const float4* cdst4 = (const float4*)cdst;

    for (int c = 0; c < 16; c++) {          // 16 chunks x 16 keys = 256 keys
        __syncthreads();
        for (int e = tid; e < 3072; e += 512) {
            int kl = e / 24, d = e % 24;    // kl: 0..127 (split*16+key)
            int ssp = kl >> 4, kk = kl & 15;
            kst[e] = Kb[(size_t)(ssp*256 + c*16 + kk)*24 + d];
        }
        for (int e = tid; e < 2048; e += 512) {
            int kl = e >> 4, d = e & 15;
            int ssp = kl >> 4, kk = kl & 15;
            cdst[e] = Db[(size_t)(ssp*256 + c*16 + kk)*16 + d];
        }
        __syncthreads();
        float sc[16];
        #pragma unroll
        for (int kk = 0; kk < 16; kk++) {
            const float4* kr = &kst4[(sp*16 + kk)*6];
            float s = 0.f;
            #pragma unroll
            for (int f = 0; f < 6; f++) {
                float4 kv = kr[f];
                s = fmaf(q4[f].x, kv.x, s);
                s = fmaf(q4[f].y, kv.y, s);
                s = fmaf(q4[f].z, kv.z, s);
                s = fmaf(q4[f].w, kv.w, s);
            }
            sc[kk] = s;
        }
        float tm = m;
        #pragma unroll
        for (int kk = 0; kk < 16; kk++) tm = fmaxf(tm, sc[kk]);
        float corr = __expf(m - tm);
        m = tm; l *= corr;
        #pragma unroll
        for (int f = 0; f < 4; f++) {
            acc4[f].x *= corr; acc4[f].y *= corr;
            acc4[f].z *= corr; acc4[f].w *= corr;
        }
        #pragma unroll
        for (int kk = 0; kk < 16; kk++) {
            float e = __expf(sc[kk] - m);
            l += e;
            const float4* cr = &cdst4[(sp*16 + kk)*4];
            #pragma unroll
            for (int f = 0; f < 4; f++) {
                float4 cv = cr[f];
                acc4[f].x = fmaf(e, cv.x, acc4[f].x);
                acc4[f].y = fmaf(e, cv.y, acc4[f].y);
                acc4[f].z = fmaf(e, cv.z, acc4[f].z);
                acc4[f].w = fmaf(e, cv.w, acc4[f].w);
            }
        }
    }

    // write partials: layout [(sp*64 + r)*16 + j] -> stride-16, 2-way free
    __syncthreads();
    {
        float* pp = &part[(sp*64 + r)*16];
        pp[0] = m; pp[1] = l;
        const float* acc = (const float*)acc4;
        #pragma unroll
        for (int j = 0; j < 14; j++) pp[2+j] = acc[j];
    }
    __syncthreads();
    if (sp == 0) {
        float M = -1e30f;
        #pragma unroll
        for (int s2 = 0; s2 < 8; s2++) M = fmaxf(M, part[(s2*64 + r)*16]);
        float L = 0.f, o[14];
        #pragma unroll
        for (int j = 0; j < 14; j++) o[j] = 0.f;
        #pragma unroll
        for (int s2 = 0; s2 < 8; s2++) {
            const float* pp = &part[(s2*64 + r)*16];
            float w = __expf(pp[0] - M);
            L += w * pp[1];
            #pragma unroll
            for (int j = 0; j < 14; j++) o[j] = fmaf(w, pp[2+j], o[j]);
        }
        float inv = 1.f / L;
        int b = bh >> 2, h = bh & 3;
        float* xo = ws + OFF_XO + ((size_t)b*2048 + row)*112 + h*14;
        #pragma unroll
        for (int j = 0; j < 14; j++) xo[j] = fmaxf(o[j]*inv, 0.f);
    }
}

// ---------------- out = mp + concat(xo,cA) @ Wout^T + bout ----------------
__global__ __launch_bounds__(128) void finalk(const float* __restrict__ bout,
    float* __restrict__ ws, float* __restrict__ out)
{
    __shared__ float xr[896];               // 8 rows x 112
    const float* Wo = ws + OFF_WOUT;
    int p0 = blockIdx.x * 8, tid = threadIdx.x;
    for (int e = tid; e < 896; e += 128) xr[e] = ws[OFF_XO + p0*112 + e];
    __syncthreads();
    if (tid < 88) {
        int o = tid; float bb = bout[o];
        float acc[8];
        #pragma unroll
        for (int p = 0; p < 8; p++) acc[p] = bb;
        for (int i = 0; i < 112; i++) {
            float w = Wo[i*88 + o];
            #pragma unroll
            for (int p = 0; p < 8; p++) acc[p] = fmaf(xr[p*112+i], w, acc[p]);
        }
        #pragma unroll
        for (int p = 0; p < 8; p++)
            out[(p0+p)*88 + o] = acc[p] + ws[OFF_MP + (p0+p)*88 + o];
    }
}

extern "C" void kernel_launch(void* const* d_in, const int* in_sizes, int n_in,
                              void* d_out, int out_size, void* d_ws, size_t ws_size,
                              hipStream_t stream) {
    const float* x    = (const float*)d_in[0];
    const float* w1   = (const float*)d_in[1];
    const float* w2a  = (const float*)d_in[2];
    const float* w2b  = (const float*)d_in[3];
    const float* w3a  = (const float*)d_in[4];
    const float* w3b  = (const float*)d_in[5];
    const float* w3c  = (const float*)d_in[6];
    const float* g1   = (const float*)d_in[7];
    const float* g2a  = (const float*)d_in[8];
    const float* g2b  = (const float*)d_in[9];
    const float* g3a  = (const float*)d_in[10];
    const float* g3b  = (const float*)d_in[11];
    const float* g3c  = (const float*)d_in[12];
    const float* b1   = (const float*)d_in[13];
    const float* b2a  = (const float*)d_in[14];
    const float* b2b  = (const float*)d_in[15];
    const float* b3a  = (const float*)d_in[16];
    const float* b3b  = (const float*)d_in[17];
    const float* b3c  = (const float*)d_in[18];
    const float* Wmp  = (const float*)d_in[19];
    const float* bmp  = (const float*)d_in[20];
    const float* Wq   = (const float*)d_in[21];
    const float* Wk   = (const float*)d_in[22];
    const float* Wv   = (const float*)d_in[23];
    const float* Wout = (const float*)d_in[24];
    const float* bout = (const float*)d_in[25];
    float* ws = (float*)d_ws;
    float* out = (float*)d_out;

    prepk<<<645, 256, 0, stream>>>(w1, w2a, w2b, w3a, w3b, w3c,
                                   g1, g2a, g2b, g3a, g3b, g3c,
                                   b1, b2a, b3a, Wmp, Wq, Wk, Wv, Wout, ws);
    conv1k<<<1024, 256, 0, stream>>>(x, ws);
    conv3k<<<dim3(1024, 2), 128, 0, stream>>>(ws, b2b, b3b);
    conv5k<<<1024, 128, 0, stream>>>(ws, b3c);
    mpk<<<1024, 128, 0, stream>>>(x, bmp, ws);
    qkvk<<<1024, 128, 0, stream>>>(ws);
    attnk<<<dim3(32, 16), 512, 0, stream>>>(ws);
    finalk<<<1024, 128, 0, stream>>>(bout, ws, out);
}

// Round 3
// 340.407 us; speedup vs baseline: 3.0996x; 1.0838x over previous
//
#include <hip/hip_runtime.h>

#define BN_INV  0.99999500003749981f
#define QSCALE  0.21320071635561041f   // 22^-0.5

typedef unsigned int uint;
typedef unsigned short u16;
typedef __attribute__((ext_vector_type(8))) short s16x8;
typedef __attribute__((ext_vector_type(4))) float f32x4;

// ---- ws layout (float offsets) ----
#define OFF_BCAT 0         // 264 fp32
// bf16 weight tables, [Npad][Ktot] u16, offsets in SHORTS:
#define SB1    1024        // 320 x 96
#define SB2B   31744       // 128 x 288
#define SB3B   68608       // 128 x 288
#define SB3C   105472      // 128 x 480
#define SBMP   166912      // 128 x 288
#define SBQKV  203776      // 384 x 96
#define SBOUT  240640      // 128 x 192   (ends 265216 sh = 132608 fl)
// activations (fp32):
#define OFF_XCAT 165000    // 8192*264 (t1|t2a|t3a) -- dead after mp
#define OFF_Q    165000    // 16*2048*24 overlays XCAT
#define OFF_K    951432    // 16*2048*24
#define OFF_CD   1737864   // 16*2048*16
#define OFF_X2   2327688   // 8192*88 -- dead after mp
#define OFF_XO   2327688   // 8192*112 overlays X2
#define OFF_T3B  3048584   // 8192*88 -- dead after conv5
#define OFF_X3   3769480   // 8192*88 -- dead after mp
#define OFF_V    3769480   // 8192*88 overlays X3 (qkv output)
#define OFF_MP   4490376   // 8192*88

__constant__ float c_dlo[8] = {-0.010597401784997278f, 0.032883011666982945f,
    0.030841381835986965f, -0.18703481171888114f, -0.02798376941698385f,
    0.6308807679295904f, 0.7148465705525415f, 0.23037781330885523f};
__constant__ float c_dhi[8] = {-0.23037781330885523f, 0.7148465705525415f,
    -0.6308807679295904f, -0.02798376941698385f, 0.18703481171888114f,
    0.030841381835986965f, -0.032883011666982945f, -0.010597401784997278f};

__device__ __forceinline__ u16 f2bf(float f) {
    uint u = __float_as_uint(f);
    uint r = u + 0x7fffu + ((u >> 16) & 1u);
    return (u16)(r >> 16);
}

// ---------------- weight prep: fold BN, transpose to [N][K] bf16 ----------
__global__ __launch_bounds__(256) void prepk(
    const float* __restrict__ w1, const float* __restrict__ w2a, const float* __restrict__ w2b,
    const float* __restrict__ w3a, const float* __restrict__ w3b, const float* __restrict__ w3c,
    const float* __restrict__ g1, const float* __restrict__ g2a, const float* __restrict__ g2b,
    const float* __restrict__ g3a, const float* __restrict__ g3b, const float* __restrict__ g3c,
    const float* __restrict__ b1, const float* __restrict__ b2a, const float* __restrict__ b3a,
    const float* __restrict__ Wmp, const float* __restrict__ Wq, const float* __restrict__ Wk,
    const float* __restrict__ Wv, const float* __restrict__ Wout, float* __restrict__ ws)
{
    u16* wu = (u16*)ws;
    int r = blockIdx.x * 256 + threadIdx.x;
    if (r < 264) {
        ws[OFF_BCAT + r] = (r < 88) ? b1[r] : (r < 176 ? b2a[r-88] : b3a[r-176]);
        return;
    }
    r -= 264;
    if (r < 320*96) {                       // WB1: cat(w1,w2a,w3a) folded
        int n = r / 96, kk = r % 96; float v = 0.f;
        if (kk < 88 && n < 264) {
            if (n < 88)       v = w1 [n*88+kk]       * g1 [n];
            else if (n < 176) v = w2a[(n-88)*88+kk]  * g2a[n-88];
            else              v = w3a[(n-176)*88+kk] * g3a[n-176];
            v *= BN_INV;
        }
        wu[SB1 + r] = f2bf(v); return;
    }
    r -= 320*96;
    if (r < 128*288) {                      // WB2B
        int n = r / 288, kk = r % 288, t = kk/96, i = kk%96; float v = 0.f;
        if (n < 88 && i < 88) v = w2b[n*264 + i*3 + t] * g2b[n] * BN_INV;
        wu[SB2B + r] = f2bf(v); return;
    }
    r -= 128*288;
    if (r < 128*288) {                      // WB3B
        int n = r / 288, kk = r % 288, t = kk/96, i = kk%96; float v = 0.f;
        if (n < 88 && i < 88) v = w3b[n*264 + i*3 + t] * g3b[n] * BN_INV;
        wu[SB3B + r] = f2bf(v); return;
    }
    r -= 128*288;
    if (r < 128*480) {                      // WB3C
        int n = r / 480, kk = r % 480, t = kk/96, i = kk%96; float v = 0.f;
        if (n < 88 && i < 88) v = w3c[n*440 + i*5 + t] * g3c[n] * BN_INV;
        wu[SB3C + r] = f2bf(v); return;
    }
    r -= 128*480;
    if (r < 128*288) {                      // WBMP
        int n = r / 288, kk = r % 288, c = kk/96, i = kk%96; float v = 0.f;
        if (n < 88 && i < 88) v = Wmp[n*264 + c*88 + i];
        wu[SBMP + r] = f2bf(v); return;
    }
    r -= 128*288;
    if (r < 384*96) {                       // WBQKV (q-scale folded)
        int n = r / 96, kk = r % 96, sec = n / 128, o = n % 128; float v = 0.f;
        if (o < 88 && kk < 88) {
            if (sec == 0)      v = Wq[o*88+kk] * QSCALE;
            else if (sec == 1) v = Wk[o*88+kk];
            else               v = Wv[o*88+kk];
        }
        wu[SBQKV + r] = f2bf(v); return;
    }
    r -= 384*96;
    if (r < 128*192) {                      // WBOUT
        int n = r / 192, kk = r % 192; float v = 0.f;
        if (n < 88 && kk < 112) v = Wout[n*112 + kk];
        wu[SBOUT + r] = f2bf(v); return;
    }
}

// ---------------- generic bf16 MFMA GEMM, 64x64 tile, K-chunks of 96 ------
struct GemmChunks {
    const float* src[5];
    int stride[5];
    int shift[5];
    int cols[5];
};

// MODE 0: out[row*outStride+col] = acc + bias[col] (+relu) (+resid)
// MODE 1: qkv scatter (out = ws base)
template<int NCH, int MODE>
__global__ __launch_bounds__(256) void gemmk(GemmChunks ch,
    const u16* __restrict__ Bw, int Ktot,
    const float* __restrict__ bias, const float* __restrict__ resid, int relu,
    float* __restrict__ out, int outStride, int N)
{
    __shared__ u16 As[64*104];
    __shared__ u16 Bs[64*104];
    int tid = threadIdx.x;
    int lane = tid & 63, w = tid >> 6, wr = w >> 1, wc = w & 1;
    int p0 = blockIdx.x * 64;
    int nb = blockIdx.y;
    int bs = p0 & ~2047, be = bs + 2048;

    f32x4 acc[2][2];
    #pragma unroll
    for (int a = 0; a < 2; a++)
        #pragma unroll
        for (int b = 0; b < 2; b++) acc[a][b] = (f32x4){0.f,0.f,0.f,0.f};

    int ar0 = (wr*32 + (lane&15))*104 + (lane>>4)*8;
    int br0 = (wc*32 + (lane&15))*104 + (lane>>4)*8;

    for (int c = 0; c < NCH; c++) {
        const float* src = ch.src[c];
        int stride = ch.stride[c], shift = ch.shift[c], cols = ch.cols[c];
        __syncthreads();
        // stage A: 64 rows x 96 k (fp32 -> bf16), zero-pad invalid
        for (int e = tid; e < 3072; e += 256) {
            int r = e / 48, kp = (e % 48) * 2;
            int row = p0 + r + shift;
            uint val = 0;
            if (row >= bs && row < be && kp < cols) {
                float2 f = *(const float2*)&src[(size_t)row*stride + kp];
                val = ((uint)f2bf(f.y) << 16) | (uint)f2bf(f.x);
            }
            *(uint*)&As[r*104 + kp] = val;
        }
        // stage B: 64 n-rows x 96 k (bf16 [N][K] global, 16B vector loads)
        for (int e = tid; e < 768; e += 256) {
            int n = e / 12, seg = e % 12;
            *(int4*)&Bs[n*104 + seg*8] =
                *(const int4*)&Bw[((size_t)(nb*64 + n))*Ktot + c*96 + seg*8];
        }
        __syncthreads();
        #pragma unroll
        for (int ks = 0; ks < 3; ks++) {
            s16x8 a0 = *(const s16x8*)&As[ar0 + ks*32];
            s16x8 a1 = *(const s16x8*)&As[ar0 + 16*104 + ks*32];
            s16x8 b0 = *(const s16x8*)&Bs[br0 + ks*32];
            s16x8 b1 = *(const s16x8*)&Bs[br0 + 16*104 + ks*32];
            acc[0][0] = __builtin_amdgcn_mfma_f32_16x16x32_bf16(a0, b0, acc[0][0], 0, 0, 0);
            acc[0][1] = __builtin_amdgcn_mfma_f32_16x16x32_bf16(a0, b1, acc[0][1], 0, 0, 0);
            acc[1][0] = __builtin_amdgcn_mfma_f32_16x16x32_bf16(a1, b0, acc[1][0], 0, 0, 0);
            acc[1][1] = __builtin_amdgcn_mfma_f32_16x16x32_bf16(a1, b1, acc[1][1], 0, 0, 0);
        }
    }

    int rbase = p0 + wr*32 + (lane>>4)*4;
    if (MODE == 0) {
        int cbase = nb*64 + wc*32 + (lane&15);
        #pragma unroll
        for (int fn = 0; fn < 2; fn++) {
            int col = cbase + fn*16;
            if (col < N) {
                float bb = bias ? bias[col] : 0.f;
                #pragma unroll
                for (int fm = 0; fm < 2; fm++)
                    #pragma unroll
                    for (int j = 0; j < 4; j++) {
                        int row = rbase + fm*16 + j;
                        float v = acc[fm][fn][j] + bb;
                        if (relu) v = fmaxf(v, 0.f);
                        if (resid) v += resid[(size_t)row*outStride + col];
                        out[(size_t)row*outStride + col] = v;
                    }
            }
        }
    } else {
        // qkv scatter: out = ws base
        int sec = nb >> 1;
        #pragma unroll
        for (int fn = 0; fn < 2; fn++) {
            int cw = (nb&1)*64 + wc*32 + fn*16 + (lane&15);
            if (cw < 88) {
                int h = cw / 22, d = cw % 22;
                #pragma unroll
                for (int fm = 0; fm < 2; fm++)
                    #pragma unroll
                    for (int j = 0; j < 4; j++) {
                        int row = rbase + fm*16 + j;
                        int b = row >> 11, s = row & 2047;
                        float v = acc[fm][fn][j];
                        if (sec == 0)
                            out[OFF_Q + ((size_t)(b*4+h)*2048 + s)*24 + d] = v;
                        else if (sec == 1)
                            out[OFF_K + ((size_t)(b*4+h)*2048 + s)*24 + d] = v;
                        else
                            out[OFF_V + (size_t)row*88 + cw] = v;
                    }
            }
        }
    }
}

// ---------------- DWT(V) + cA scatter + pad zeroing -----------------------
__global__ __launch_bounds__(256) void dwtk(float* __restrict__ ws)
{
    int tid = threadIdx.x;
    int p0 = blockIdx.x * 16;
    const float* V = ws + OFF_V;
    for (int e = tid; e < 896; e += 256) {
        int p = e / 56, rr = e % 56, h = rr / 14, jj = rr % 14;
        int pos = p0 + p, b = pos >> 11, s = pos & 2047;
        const float* v = &V[(size_t)pos*88 + h*22];
        float ca = 0.f, cd = 0.f;
        #pragma unroll
        for (int t = 0; t < 8; t++) {
            int pp = 1 + 2*jj + t;
            int oi = pp < 7 ? 6 - pp : (pp < 29 ? pp - 7 : 50 - pp);
            float vv = v[oi];
            ca = fmaf(vv, c_dlo[7-t], ca);
            cd = fmaf(vv, c_dhi[7-t], cd);
        }
        ws[OFF_CD + ((size_t)(b*4+h)*2048 + s)*16 + jj] = cd;
        int hs = h*2048 + s, s2 = hs >> 2, qd = hs & 3;
        ws[OFF_XO + ((size_t)b*2048 + s2)*112 + 56 + qd*14 + jj] = ca;
    }
    // pads: Q/K d=22,23 (all 4 h), cD d=14,15 (all 4 h): 24 zeros per row
    for (int e = tid; e < 384; e += 256) {
        int p = e / 24, t = e % 24;
        int pos = p0 + p, b = pos >> 11, s = pos & 2047;
        if (t < 8)
            ws[OFF_Q + ((size_t)(b*4 + (t>>1))*2048 + s)*24 + 22 + (t&1)] = 0.f;
        else if (t < 16) {
            int tt = t - 8;
            ws[OFF_K + ((size_t)(b*4 + (tt>>1))*2048 + s)*24 + 22 + (tt&1)] = 0.f;
        } else {
            int tt = t - 16;
            ws[OFF_CD + ((size_t)(b*4 + (tt>>1))*2048 + s)*16 + 14 + (tt&1)] = 0.f;
        }
    }
}

// ---------------- flash attention, in-block split-K (unchanged) -----------
__global__ __launch_bounds__(512, 4) void attnk(float* __restrict__ ws)
{
    __shared__ float kst[8*16*24];
    __shared__ float cdst[8*16*16];
    __shared__ float part[512*16];
    int tid = threadIdx.x;
    int sp = tid >> 6, r = tid & 63;
    int bh = blockIdx.y;
    int row = blockIdx.x * 64 + r;
    const float* Qb = ws + OFF_Q  + (size_t)bh*2048*24;
    const float* Kb = ws + OFF_K  + (size_t)bh*2048*24;
    const float* Db = ws + OFF_CD + (size_t)bh*2048*16;

    float4 q4[6];
    const float4* qp = (const float4*)&Qb[row*24];
    #pragma unroll
    for (int f = 0; f < 6; f++) q4[f] = qp[f];

    float m = -1e30f, l = 0.f;
    float4 acc4[4];
    #pragma unroll
    for (int f = 0; f < 4; f++) acc4[f] = make_float4(0.f, 0.f, 0.f, 0.f);

    const float4* kst4 = (const float4*)kst;
    const float4* cdst4 = (const float4*)cdst;

    for (int c = 0; c < 16; c++) {
        __syncthreads();
        for (int e = tid; e < 3072; e += 512) {
            int kl = e / 24, d = e % 24;
            int ssp = kl >> 4, kk = kl & 15;
            kst[e] = Kb[(size_t)(ssp*256 + c*16 + kk)*24 + d];
        }
        for (int e = tid; e < 2048; e += 512) {
            int kl = e >> 4, d = e & 15;
            int ssp = kl >> 4, kk = kl & 15;
            cdst[e] = Db[(size_t)(ssp*256 + c*16 + kk)*16 + d];
        }
        __syncthreads();
        float sc[16];
        #pragma unroll
        for (int kk = 0; kk < 16; kk++) {
            const float4* kr = &kst4[(sp*16 + kk)*6];
            float s = 0.f;
            #pragma unroll
            for (int f = 0; f < 6; f++) {
                float4 kv = kr[f];
                s = fmaf(q4[f].x, kv.x, s);
                s = fmaf(q4[f].y, kv.y, s);
                s = fmaf(q4[f].z, kv.z, s);
                s = fmaf(q4[f].w, kv.w, s);
            }
            sc[kk] = s;
        }
        float tm = m;
        #pragma unroll
        for (int kk = 0; kk < 16; kk++) tm = fmaxf(tm, sc[kk]);
        float corr = __expf(m - tm);
        m = tm; l *= corr;
        #pragma unroll
        for (int f = 0; f < 4; f++) {
            acc4[f].x *= corr; acc4[f].y *= corr;
            acc4[f].z *= corr; acc4[f].w *= corr;
        }
        #pragma unroll
        for (int kk = 0; kk < 16; kk++) {
            float e = __expf(sc[kk] - m);
            l += e;
            const float4* cr = &cdst4[(sp*16 + kk)*4];
            #pragma unroll
            for (int f = 0; f < 4; f++) {
                float4 cv = cr[f];
                acc4[f].x = fmaf(e, cv.x, acc4[f].x);
                acc4[f].y = fmaf(e, cv.y, acc4[f].y);
                acc4[f].z = fmaf(e, cv.z, acc4[f].z);
                acc4[f].w = fmaf(e, cv.w, acc4[f].w);
            }
        }
    }

    __syncthreads();
    {
        float* pp = &part[(sp*64 + r)*16];
        pp[0] = m; pp[1] = l;
        const float* acc = (const float*)acc4;
        #pragma unroll
        for (int j = 0; j < 14; j++) pp[2+j] = acc[j];
    }
    __syncthreads();
    if (sp == 0) {
        float M = -1e30f;
        #pragma unroll
        for (int s2 = 0; s2 < 8; s2++) M = fmaxf(M, part[(s2*64 + r)*16]);
        float L = 0.f, o[14];
        #pragma unroll
        for (int j = 0; j < 14; j++) o[j] = 0.f;
        #pragma unroll
        for (int s2 = 0; s2 < 8; s2++) {
            const float* pp = &part[(s2*64 + r)*16];
            float w = __expf(pp[0] - M);
            L += w * pp[1];
            #pragma unroll
            for (int j = 0; j < 14; j++) o[j] = fmaf(w, pp[2+j], o[j]);
        }
        float inv = 1.f / L;
        int b = bh >> 2, h = bh & 3;
        float* xo = ws + OFF_XO + ((size_t)b*2048 + row)*112 + h*14;
        #pragma unroll
        for (int j = 0; j < 14; j++) xo[j] = fmaxf(o[j]*inv, 0.f);
    }
}

extern "C" void kernel_launch(void* const* d_in, const int* in_sizes, int n_in,
                              void* d_out, int out_size, void* d_ws, size_t ws_size,
                              hipStream_t stream) {
    const float* x    = (const float*)d_in[0];
    const float* w1   = (const float*)d_in[1];
    const float* w2a  = (const float*)d_in[2];
    const float* w2b  = (const float*)d_in[3];
    const float* w3a  = (const float*)d_in[4];
    const float* w3b  = (const float*)d_in[5];
    const float* w3c  = (const float*)d_in[6];
    const float* g1   = (const float*)d_in[7];
    const float* g2a  = (const float*)d_in[8];
    const float* g2b  = (const float*)d_in[9];
    const float* g3a  = (const float*)d_in[10];
    const float* g3b  = (const float*)d_in[11];
    const float* g3c  = (const float*)d_in[12];
    const float* b1   = (const float*)d_in[13];
    const float* b2a  = (const float*)d_in[14];
    const float* b2b  = (const float*)d_in[15];
    const float* b3a  = (const float*)d_in[16];
    const float* b3b  = (const float*)d_in[17];
    const float* b3c  = (const float*)d_in[18];
    const float* Wmp  = (const float*)d_in[19];
    const float* bmp  = (const float*)d_in[20];
    const float* Wq   = (const float*)d_in[21];
    const float* Wk   = (const float*)d_in[22];
    const float* Wv   = (const float*)d_in[23];
    const float* Wout = (const float*)d_in[24];
    const float* bout = (const float*)d_in[25];
    float* ws = (float*)d_ws;
    float* out = (float*)d_out;
    const u16* wu = (const u16*)d_ws;

    prepk<<<1034, 256, 0, stream>>>(w1, w2a, w2b, w3a, w3b, w3c,
                                    g1, g2a, g2b, g3a, g3b, g3c,
                                    b1, b2a, b3a, Wmp, Wq, Wk, Wv, Wout, ws);

    // conv1: x[8192x88] @ WB1 -> XCAT[8192x264], bias BCAT, relu
    {
        GemmChunks c{}; c.src[0]=x; c.stride[0]=88; c.shift[0]=0; c.cols[0]=88;
        gemmk<1,0><<<dim3(128,5), 256, 0, stream>>>(c, wu+SB1, 96,
            ws+OFF_BCAT, nullptr, 1, ws+OFF_XCAT, 264, 264);
    }
    // conv3a: shifts of XCAT[:,88:176] @ WB2B -> X2, bias b2b, relu
    {
        GemmChunks c{};
        for (int t = 0; t < 3; t++) { c.src[t]=ws+OFF_XCAT+88; c.stride[t]=264; c.shift[t]=t-1; c.cols[t]=88; }
        gemmk<3,0><<<dim3(128,2), 256, 0, stream>>>(c, wu+SB2B, 288,
            b2b, nullptr, 1, ws+OFF_X2, 88, 88);
    }
    // conv3b: shifts of XCAT[:,176:264] @ WB3B -> T3B, bias b3b, relu
    {
        GemmChunks c{};
        for (int t = 0; t < 3; t++) { c.src[t]=ws+OFF_XCAT+176; c.stride[t]=264; c.shift[t]=t-1; c.cols[t]=88; }
        gemmk<3,0><<<dim3(128,2), 256, 0, stream>>>(c, wu+SB3B, 288,
            b3b, nullptr, 1, ws+OFF_T3B, 88, 88);
    }
    // conv5: shifts of T3B @ WB3C -> X3, bias b3c, relu
    {
        GemmChunks c{};
        for (int t = 0; t < 5; t++) { c.src[t]=ws+OFF_T3B; c.stride[t]=88; c.shift[t]=t-2; c.cols[t]=88; }
        gemmk<5,0><<<dim3(128,2), 256, 0, stream>>>(c, wu+SB3C, 480,
            b3c, nullptr, 1, ws+OFF_X3, 88, 88);
    }
    // mp: cat(x1,x2,x3) @ WBMP + bmp + x -> MP
    {
        GemmChunks c{};
        c.src[0]=ws+OFF_XCAT; c.stride[0]=264; c.shift[0]=0; c.cols[0]=88;
        c.src[1]=ws+OFF_X2;   c.stride[1]=88;  c.shift[1]=0; c.cols[1]=88;
        c.src[2]=ws+OFF_X3;   c.stride[2]=88;  c.shift[2]=0; c.cols[2]=88;
        gemmk<3,0><<<dim3(128,2), 256, 0, stream>>>(c, wu+SBMP, 288,
            bmp, x, 0, ws+OFF_MP, 88, 88);
    }
    // qkv: MP @ WBQKV -> scatter Q,K,V
    {
        GemmChunks c{}; c.src[0]=ws+OFF_MP; c.stride[0]=88; c.shift[0]=0; c.cols[0]=88;
        gemmk<1,1><<<dim3(128,6), 256, 0, stream>>>(c, wu+SBQKV, 96,
            nullptr, nullptr, 0, ws, 0, 0);
    }
    dwtk<<<512, 256, 0, stream>>>(ws);
    attnk<<<dim3(32, 16), 512, 0, stream>>>(ws);
    // final: XO[8192x112] @ WBOUT + bout + MP -> out
    {
        GemmChunks c{};
        c.src[0]=ws+OFF_XO;    c.stride[0]=112; c.shift[0]=0; c.cols[0]=96;
        c.src[1]=ws+OFF_XO+96; c.stride[1]=112; c.shift[1]=0; c.cols[1]=16;
        gemmk<2,0><<<dim3(128,2), 256, 0, stream>>>(c, wu+SBOUT, 192,
            bout, ws+OFF_MP, 0, out, 88, 88);
    }
}

// Round 5
// 268.092 us; speedup vs baseline: 3.9356x; 1.2697x over previous
//
#include <hip/hip_runtime.h>

#define BN_INV  0.99999500003749981f
#define QSCALE  0.21320071635561041f   // 22^-0.5

typedef unsigned int uint;
typedef unsigned short u16;
typedef __attribute__((ext_vector_type(8))) short s16x8;
typedef __attribute__((ext_vector_type(4))) float f32x4;

// ---- ws layout ----
#define OFF_BCAT 0         // 264 fp32
// bf16 weight tables, [Npad][Ktot] u16, offsets in SHORTS:
#define SB1    1024        // 320 x 96
#define SB2B   31744       // 128 x 288
#define SB3B   68608       // 128 x 288
#define SB3C   105472      // 128 x 480
#define SBMP   166912      // 128 x 288
#define SBQKV  203776      // 384 x 96
#define SBOUT  240640      // 128 x 192   (ends 265216 sh = 132608 fl)
// activations:
#define OFF_XCAT 165000    // fp32 8192*264 (t1|t2a|t3a) -- dead after mp
// bf16 attention operands (short offsets), overlay XCAT region (written post-mp):
#define SQB    330000      // Qb bf16 [16][2048][32]
#define SKB    1378576     // Kb bf16 [16][2048][32]
#define SCDT   2427152     // CDT bf16 [16][16][2048]  (ends 2951440 sh)
#define OFF_X2   2327688   // fp32 8192*88 -- dead after mp
#define OFF_XO   2327688   // fp32 8192*112 overlays X2
#define OFF_T3B  3048584   // fp32 8192*88 -- dead after conv5
#define OFF_X3   3769480   // fp32 8192*88 -- dead after mp
#define OFF_V    3769480   // fp32 8192*88 overlays X3 (qkv output)
#define OFF_MP   4490376   // fp32 8192*88

__constant__ float c_dlo[8] = {-0.010597401784997278f, 0.032883011666982945f,
    0.030841381835986965f, -0.18703481171888114f, -0.02798376941698385f,
    0.6308807679295904f, 0.7148465705525415f, 0.23037781330885523f};
__constant__ float c_dhi[8] = {-0.23037781330885523f, 0.7148465705525415f,
    -0.6308807679295904f, -0.02798376941698385f, 0.18703481171888114f,
    0.030841381835986965f, -0.032883011666982945f, -0.010597401784997278f};

__device__ __forceinline__ u16 f2bf(float f) {
    uint u = __float_as_uint(f);
    uint r = u + 0x7fffu + ((u >> 16) & 1u);
    return (u16)(r >> 16);
}

// ---------------- weight prep: fold BN, transpose to [N][K] bf16 ----------
__global__ __launch_bounds__(256) void prepk(
    const float* __restrict__ w1, const float* __restrict__ w2a, const float* __restrict__ w2b,
    const float* __restrict__ w3a, const float* __restrict__ w3b, const float* __restrict__ w3c,
    const float* __restrict__ g1, const float* __restrict__ g2a, const float* __restrict__ g2b,
    const float* __restrict__ g3a, const float* __restrict__ g3b, const float* __restrict__ g3c,
    const float* __restrict__ b1, const float* __restrict__ b2a, const float* __restrict__ b3a,
    const float* __restrict__ Wmp, const float* __restrict__ Wq, const float* __restrict__ Wk,
    const float* __restrict__ Wv, const float* __restrict__ Wout, float* __restrict__ ws)
{
    u16* wu = (u16*)ws;
    int r = blockIdx.x * 256 + threadIdx.x;
    if (r < 264) {
        ws[OFF_BCAT + r] = (r < 88) ? b1[r] : (r < 176 ? b2a[r-88] : b3a[r-176]);
        return;
    }
    r -= 264;
    if (r < 320*96) {                       // WB1: cat(w1,w2a,w3a) folded
        int n = r / 96, kk = r % 96; float v = 0.f;
        if (kk < 88 && n < 264) {
            if (n < 88)       v = w1 [n*88+kk]       * g1 [n];
            else if (n < 176) v = w2a[(n-88)*88+kk]  * g2a[n-88];
            else              v = w3a[(n-176)*88+kk] * g3a[n-176];
            v *= BN_INV;
        }
        wu[SB1 + r] = f2bf(v); return;
    }
    r -= 320*96;
    if (r < 128*288) {                      // WB2B
        int n = r / 288, kk = r % 288, t = kk/96, i = kk%96; float v = 0.f;
        if (n < 88 && i < 88) v = w2b[n*264 + i*3 + t] * g2b[n] * BN_INV;
        wu[SB2B + r] = f2bf(v); return;
    }
    r -= 128*288;
    if (r < 128*288) {                      // WB3B
        int n = r / 288, kk = r % 288, t = kk/96, i = kk%96; float v = 0.f;
        if (n < 88 && i < 88) v = w3b[n*264 + i*3 + t] * g3b[n] * BN_INV;
        wu[SB3B + r] = f2bf(v); return;
    }
    r -= 128*288;
    if (r < 128*480) {                      // WB3C
        int n = r / 480, kk = r % 480, t = kk/96, i = kk%96; float v = 0.f;
        if (n < 88 && i < 88) v = w3c[n*440 + i*5 + t] * g3c[n] * BN_INV;
        wu[SB3C + r] = f2bf(v); return;
    }
    r -= 128*480;
    if (r < 128*288) {                      // WBMP
        int n = r / 288, kk = r % 288, c = kk/96, i = kk%96; float v = 0.f;
        if (n < 88 && i < 88) v = Wmp[n*264 + c*88 + i];
        wu[SBMP + r] = f2bf(v); return;
    }
    r -= 128*288;
    if (r < 384*96) {                       // WBQKV (q-scale folded)
        int n = r / 96, kk = r % 96, sec = n / 128, o = n % 128; float v = 0.f;
        if (o < 88 && kk < 88) {
            if (sec == 0)      v = Wq[o*88+kk] * QSCALE;
            else if (sec == 1) v = Wk[o*88+kk];
            else               v = Wv[o*88+kk];
        }
        wu[SBQKV + r] = f2bf(v); return;
    }
    r -= 384*96;
    if (r < 128*192) {                      // WBOUT
        int n = r / 192, kk = r % 192; float v = 0.f;
        if (n < 88 && kk < 112) v = Wout[n*112 + kk];
        wu[SBOUT + r] = f2bf(v); return;
    }
}

// ---------------- generic bf16 MFMA GEMM, 64x64 tile, K-chunks of 96 ------
struct GemmChunks {
    const float* src[5];
    int stride[5];
    int shift[5];
    int cols[5];
};

// MODE 0: out[row*outStride+col] = acc + bias[col] (+relu) (+resid)
// MODE 1: qkv scatter: Qb/Kb bf16 + V fp32
template<int NCH, int MODE>
__global__ __launch_bounds__(256) void gemmk(GemmChunks ch,
    const u16* __restrict__ Bw, int Ktot,
    const float* __restrict__ bias, const float* __restrict__ resid, int relu,
    float* __restrict__ out, int outStride, int N)
{
    __shared__ u16 As[64*104];
    __shared__ u16 Bs[64*104];
    int tid = threadIdx.x;
    int lane = tid & 63, w = tid >> 6, wr = w >> 1, wc = w & 1;
    int p0 = blockIdx.x * 64;
    int nb = blockIdx.y;
    int bs = p0 & ~2047, be = bs + 2048;

    f32x4 acc[2][2];
    #pragma unroll
    for (int a = 0; a < 2; a++)
        #pragma unroll
        for (int b = 0; b < 2; b++) acc[a][b] = (f32x4){0.f,0.f,0.f,0.f};

    int ar0 = (wr*32 + (lane&15))*104 + (lane>>4)*8;
    int br0 = (wc*32 + (lane&15))*104 + (lane>>4)*8;

    for (int c = 0; c < NCH; c++) {
        const float* src = ch.src[c];
        int stride = ch.stride[c], shift = ch.shift[c], cols = ch.cols[c];
        __syncthreads();
        for (int e = tid; e < 3072; e += 256) {
            int r = e / 48, kp = (e % 48) * 2;
            int row = p0 + r + shift;
            uint val = 0;
            if (row >= bs && row < be && kp < cols) {
                float2 f = *(const float2*)&src[(size_t)row*stride + kp];
                val = ((uint)f2bf(f.y) << 16) | (uint)f2bf(f.x);
            }
            *(uint*)&As[r*104 + kp] = val;
        }
        for (int e = tid; e < 768; e += 256) {
            int n = e / 12, seg = e % 12;
            *(int4*)&Bs[n*104 + seg*8] =
                *(const int4*)&Bw[((size_t)(nb*64 + n))*Ktot + c*96 + seg*8];
        }
        __syncthreads();
        #pragma unroll
        for (int ks = 0; ks < 3; ks++) {
            s16x8 a0 = *(const s16x8*)&As[ar0 + ks*32];
            s16x8 a1 = *(const s16x8*)&As[ar0 + 16*104 + ks*32];
            s16x8 b0 = *(const s16x8*)&Bs[br0 + ks*32];
            s16x8 b1 = *(const s16x8*)&Bs[br0 + 16*104 + ks*32];
            acc[0][0] = __builtin_amdgcn_mfma_f32_16x16x32_bf16(a0, b0, acc[0][0], 0, 0, 0);
            acc[0][1] = __builtin_amdgcn_mfma_f32_16x16x32_bf16(a0, b1, acc[0][1], 0, 0, 0);
            acc[1][0] = __builtin_amdgcn_mfma_f32_16x16x32_bf16(a1, b0, acc[1][0], 0, 0, 0);
            acc[1][1] = __builtin_amdgcn_mfma_f32_16x16x32_bf16(a1, b1, acc[1][1], 0, 0, 0);
        }
    }

    int rbase = p0 + wr*32 + (lane>>4)*4;
    if (MODE == 0) {
        int cbase = nb*64 + wc*32 + (lane&15);
        #pragma unroll
        for (int fn = 0; fn < 2; fn++) {
            int col = cbase + fn*16;
            if (col < N) {
                float bb = bias ? bias[col] : 0.f;
                #pragma unroll
                for (int fm = 0; fm < 2; fm++)
                    #pragma unroll
                    for (int j = 0; j < 4; j++) {
                        int row = rbase + fm*16 + j;
                        float v = acc[fm][fn][j] + bb;
                        if (relu) v = fmaxf(v, 0.f);
                        if (resid) v += resid[(size_t)row*outStride + col];
                        out[(size_t)row*outStride + col] = v;
                    }
            }
        }
    } else {
        u16* wq = (u16*)out;
        int sec = nb >> 1;
        #pragma unroll
        for (int fn = 0; fn < 2; fn++) {
            int cw = (nb&1)*64 + wc*32 + fn*16 + (lane&15);
            if (cw < 88) {
                int h = cw / 22, d = cw % 22;
                #pragma unroll
                for (int fm = 0; fm < 2; fm++)
                    #pragma unroll
                    for (int j = 0; j < 4; j++) {
                        int row = rbase + fm*16 + j;
                        int b = row >> 11, s = row & 2047;
                        float v = acc[fm][fn][j];
                        if (sec == 0)
                            wq[SQB + ((size_t)(b*4+h)*2048 + s)*32 + d] = f2bf(v);
                        else if (sec == 1)
                            wq[SKB + ((size_t)(b*4+h)*2048 + s)*32 + d] = f2bf(v);
                        else
                            out[OFF_V + (size_t)row*88 + cw] = v;
                    }
            }
        }
    }
}

// ---------------- DWT(V) -> CDT bf16 + cA scatter + pad zeroing -----------
__global__ __launch_bounds__(256) void dwtk(float* __restrict__ ws)
{
    u16* wu = (u16*)ws;
    int tid = threadIdx.x;
    int p0 = blockIdx.x * 16;
    const float* V = ws + OFF_V;
    for (int e = tid; e < 896; e += 256) {
        int p = e / 56, rr = e % 56, h = rr / 14, jj = rr % 14;
        int pos = p0 + p, b = pos >> 11, s = pos & 2047;
        const float* v = &V[(size_t)pos*88 + h*22];
        float ca = 0.f, cd = 0.f;
        #pragma unroll
        for (int t = 0; t < 8; t++) {
            int pp = 1 + 2*jj + t;
            int oi = pp < 7 ? 6 - pp : (pp < 29 ? pp - 7 : 50 - pp);
            float vv = v[oi];
            ca = fmaf(vv, c_dlo[7-t], ca);
            cd = fmaf(vv, c_dhi[7-t], cd);
        }
        wu[SCDT + ((size_t)((b*4+h)*16 + jj))*2048 + s] = f2bf(cd);
        int hs = h*2048 + s, s2 = hs >> 2, qd = hs & 3;
        ws[OFF_XO + ((size_t)b*2048 + s2)*112 + 56 + qd*14 + jj] = ca;
    }
    // zero Qb/Kb pads d=22..31 (5 uints per row per array per head)
    uint* wi = (uint*)ws;
    for (int e = tid; e < 640; e += 256) {
        int p = e / 40, t = e % 40;
        int h = t / 10, rest = t % 10, arr = rest / 5, ui = rest % 5;
        int pos = p0 + p, b = pos >> 11, s = pos & 2047;
        size_t base = (size_t)((arr ? SKB : SQB) >> 1) + ((size_t)(b*4+h)*2048 + s)*16;
        wi[base + 11 + ui] = 0;
    }
    // zero CDT rows d=14,15
    for (int e = tid; e < 128; e += 256) {
        int p = e / 8, t = e % 8, h = t >> 1, dd = 14 + (t & 1);
        int pos = p0 + p, b = pos >> 11, s = pos & 2047;
        wu[SCDT + ((size_t)((b*4+h)*16 + dd))*2048 + s] = 0;
    }
}

// ---------------- MFMA flash attention ------------------------------------
// block: 256 thr = 4 waves; grid (32 q-tiles, 16 bh). Wave w: 16 q-rows.
// S^T = K·Q^T (swapped): lane holds 16 key-scores for q=lane&15.
__global__ __launch_bounds__(256) void attnk(float* __restrict__ ws)
{
    const u16* wu = (const u16*)ws;
    __shared__ __align__(16) u16 Kt[64*40];        // 64 keys x 32d, pad 40
    __shared__ __align__(16) u16 CDt[16*72];       // 16 d x 64 keys, pad 72
    __shared__ __align__(16) u16 Pb[4][16*72];     // per-wave P [q16][key64] pad 72
    __shared__ float cb[4][16];
    __shared__ float lb[4][16];
    int tid = threadIdx.x, lane = tid & 63, w = tid >> 6;
    int bh = blockIdx.y;
    int q0 = blockIdx.x * 64 + w * 16;

    // Q fragment (B operand), constant across key loop
    s16x8 qf = *(const s16x8*)&wu[SQB + ((size_t)bh*2048 + q0 + (lane&15))*32 + (lane>>4)*8];

    const u16* Kbase = wu + SKB + (size_t)bh*2048*32;
    const u16* Cbase = wu + SCDT + (size_t)bh*16*2048;

    f32x4 o = (f32x4){0.f,0.f,0.f,0.f};
    float m = -1e30f, l = 0.f;
    int qrow = lane & 15, grp = lane >> 4;

    for (int kt = 0; kt < 32; kt++) {
        __syncthreads();
        {   // stage K tile: 64 keys x 32 d (4 KB payload)
            int r = tid >> 2, seg = tid & 3;
            *(int4*)&Kt[r*40 + seg*8] = *(const int4*)&Kbase[(size_t)(kt*64 + r)*32 + seg*8];
        }
        if (tid < 128) {  // stage cD^T tile: 16 d x 64 keys
            int d = tid >> 3, seg = tid & 7;
            *(int4*)&CDt[d*72 + seg*8] = *(const int4*)&Cbase[(size_t)d*2048 + kt*64 + seg*8];
        }
        __syncthreads();

        // QK^T: S^T[key][q], 4 key-subtiles
        f32x4 s4[4];
        #pragma unroll
        for (int sub = 0; sub < 4; sub++) {
            s16x8 kf = *(const s16x8*)&Kt[(sub*16 + qrow)*40 + grp*8];
            s4[sub] = __builtin_amdgcn_mfma_f32_16x16x32_bf16(kf, qf,
                        (f32x4){0.f,0.f,0.f,0.f}, 0, 0, 0);
        }
        float sv[16];
        #pragma unroll
        for (int sub = 0; sub < 4; sub++)
            #pragma unroll
            for (int j = 0; j < 4; j++) sv[sub*4+j] = s4[sub][j];

        float tm = sv[0];
        #pragma unroll
        for (int i = 1; i < 16; i++) tm = fmaxf(tm, sv[i]);
        tm = fmaxf(tm, __shfl_xor(tm, 16));
        tm = fmaxf(tm, __shfl_xor(tm, 32));
        float mn = fmaxf(m, tm);
        float corr = __expf(m - mn);
        m = mn;

        float ls = 0.f;
        u16 pb[16];
        #pragma unroll
        for (int i = 0; i < 16; i++) {
            float p = __expf(sv[i] - mn);
            ls += p;
            pb[i] = f2bf(p);
        }
        ls += __shfl_xor(ls, 16);
        ls += __shfl_xor(ls, 32);
        l = l * corr + ls;

        if (lane < 16) cb[w][lane] = corr;
        __builtin_amdgcn_s_waitcnt(0);  // ensure cb visible within wave (lds)
        // O rescale (corr transposed to PV row layout via LDS broadcast)
        {
            const float* cp = &cb[w][grp*4];
            #pragma unroll
            for (int j = 0; j < 4; j++) o[j] *= cp[j];
        }
        // write P (bf16) into per-wave buffer
        {
            uint* pb32 = (uint*)Pb[w];
            #pragma unroll
            for (int sub = 0; sub < 4; sub++) {
                uint u01 = (uint)pb[sub*4+0] | ((uint)pb[sub*4+1] << 16);
                uint u23 = (uint)pb[sub*4+2] | ((uint)pb[sub*4+3] << 16);
                int sa = qrow*72 + sub*16 + grp*4;
                pb32[sa >> 1] = u01;
                pb32[(sa >> 1) + 1] = u23;
            }
        }
        // PV: O[q][d] += P[q][k] * cD^T[d][k]
        #pragma unroll
        for (int ks = 0; ks < 2; ks++) {
            s16x8 pa = *(const s16x8*)&Pb[w][qrow*72 + ks*32 + grp*8];
            s16x8 cf = *(const s16x8*)&CDt[qrow*72 + ks*32 + grp*8];
            o = __builtin_amdgcn_mfma_f32_16x16x32_bf16(pa, cf, o, 0, 0, 0);
        }
    }

    if (lane < 16) lb[w][lane] = l;
    __builtin_amdgcn_s_waitcnt(0);
    {
        const float* lp = &lb[w][grp*4];
        int b = bh >> 2, h = bh & 3, d = qrow;
        if (d < 14) {
            #pragma unroll
            for (int j = 0; j < 4; j++) {
                int s = q0 + grp*4 + j;
                float val = o[j] / lp[j];
                ws[OFF_XO + ((size_t)b*2048 + s)*112 + h*14 + d] = fmaxf(val, 0.f);
            }
        }
    }
}

extern "C" void kernel_launch(void* const* d_in, const int* in_sizes, int n_in,
                              void* d_out, int out_size, void* d_ws, size_t ws_size,
                              hipStream_t stream) {
    const float* x    = (const float*)d_in[0];
    const float* w1   = (const float*)d_in[1];
    const float* w2a  = (const float*)d_in[2];
    const float* w2b  = (const float*)d_in[3];
    const float* w3a  = (const float*)d_in[4];
    const float* w3b  = (const float*)d_in[5];
    const float* w3c  = (const float*)d_in[6];
    const float* g1   = (const float*)d_in[7];
    const float* g2a  = (const float*)d_in[8];
    const float* g2b  = (const float*)d_in[9];
    const float* g3a  = (const float*)d_in[10];
    const float* g3b  = (const float*)d_in[11];
    const float* g3c  = (const float*)d_in[12];
    const float* b1   = (const float*)d_in[13];
    const float* b2a  = (const float*)d_in[14];
    const float* b2b  = (const float*)d_in[15];
    const float* b3a  = (const float*)d_in[16];
    const float* b3b  = (const float*)d_in[17];
    const float* b3c  = (const float*)d_in[18];
    const float* Wmp  = (const float*)d_in[19];
    const float* bmp  = (const float*)d_in[20];
    const float* Wq   = (const float*)d_in[21];
    const float* Wk   = (const float*)d_in[22];
    const float* Wv   = (const float*)d_in[23];
    const float* Wout = (const float*)d_in[24];
    const float* bout = (const float*)d_in[25];
    float* ws = (float*)d_ws;
    float* out = (float*)d_out;
    const u16* wu = (const u16*)d_ws;

    prepk<<<1034, 256, 0, stream>>>(w1, w2a, w2b, w3a, w3b, w3c,
                                    g1, g2a, g2b, g3a, g3b, g3c,
                                    b1, b2a, b3a, Wmp, Wq, Wk, Wv, Wout, ws);

    {   // conv1
        GemmChunks c{}; c.src[0]=x; c.stride[0]=88; c.shift[0]=0; c.cols[0]=88;
        gemmk<1,0><<<dim3(128,5), 256, 0, stream>>>(c, wu+SB1, 96,
            ws+OFF_BCAT, nullptr, 1, ws+OFF_XCAT, 264, 264);
    }
    {   // conv3a
        GemmChunks c{};
        for (int t = 0; t < 3; t++) { c.src[t]=ws+OFF_XCAT+88; c.stride[t]=264; c.shift[t]=t-1; c.cols[t]=88; }
        gemmk<3,0><<<dim3(128,2), 256, 0, stream>>>(c, wu+SB2B, 288,
            b2b, nullptr, 1, ws+OFF_X2, 88, 88);
    }
    {   // conv3b
        GemmChunks c{};
        for (int t = 0; t < 3; t++) { c.src[t]=ws+OFF_XCAT+176; c.stride[t]=264; c.shift[t]=t-1; c.cols[t]=88; }
        gemmk<3,0><<<dim3(128,2), 256, 0, stream>>>(c, wu+SB3B, 288,
            b3b, nullptr, 1, ws+OFF_T3B, 88, 88);
    }
    {   // conv5
        GemmChunks c{};
        for (int t = 0; t < 5; t++) { c.src[t]=ws+OFF_T3B; c.stride[t]=88; c.shift[t]=t-2; c.cols[t]=88; }
        gemmk<5,0><<<dim3(128,2), 256, 0, stream>>>(c, wu+SB3C, 480,
            b3c, nullptr, 1, ws+OFF_X3, 88, 88);
    }
    {   // mp
        GemmChunks c{};
        c.src[0]=ws+OFF_XCAT; c.stride[0]=264; c.shift[0]=0; c.cols[0]=88;
        c.src[1]=ws+OFF_X2;   c.stride[1]=88;  c.shift[1]=0; c.cols[1]=88;
        c.src[2]=ws+OFF_X3;   c.stride[2]=88;  c.shift[2]=0; c.cols[2]=88;
        gemmk<3,0><<<dim3(128,2), 256, 0, stream>>>(c, wu+SBMP, 288,
            bmp, x, 0, ws+OFF_MP, 88, 88);
    }
    {   // qkv -> Qb/Kb bf16 + V fp32
        GemmChunks c{}; c.src[0]=ws+OFF_MP; c.stride[0]=88; c.shift[0]=0; c.cols[0]=88;
        gemmk<1,1><<<dim3(128,6), 256, 0, stream>>>(c, wu+SBQKV, 96,
            nullptr, nullptr, 0, ws, 0, 0);
    }
    dwtk<<<512, 256, 0, stream>>>(ws);
    attnk<<<dim3(32, 16), 256, 0, stream>>>(ws);
    {   // final
        GemmChunks c{};
        c.src[0]=ws+OFF_XO;    c.stride[0]=112; c.shift[0]=0; c.cols[0]=96;
        c.src[1]=ws+OFF_XO+96; c.stride[1]=112; c.shift[1]=0; c.cols[1]=16;
        gemmk<2,0><<<dim3(128,2), 256, 0, stream>>>(c, wu+SBOUT, 192,
            bout, ws+OFF_MP, 0, out, 88, 88);
    }
}

// Round 6
// 210.372 us; speedup vs baseline: 5.0155x; 1.2744x over previous
//
#include <hip/hip_runtime.h>

#define BN_INV  0.99999500003749981f
#define QSCALE  0.21320071635561041f   // 22^-0.5

typedef unsigned int uint;
typedef unsigned short u16;
typedef __attribute__((ext_vector_type(8))) short s16x8;
typedef __attribute__((ext_vector_type(4))) float f32x4;

// ---- ws layout ----
// float offsets:
#define OFF_BCAT 0         // 264
#define OFF_V    512       // 8192*88 fp32 (qkv out, dwt in)
#define OFF_MP   721408    // 8192*88 fp32 (final residual)   ends 1442304 fl
// short offsets (shorts region starts at 2884608 sh):
#define SW0    2884608
#define SB1    (SW0)            // 320 x 96
#define SB2B   (SW0+30720)      // 128 x 288
#define SB3B   (SW0+67584)      // 128 x 288
#define SB3C   (SW0+104448)     // 128 x 480
#define SBMP   (SW0+165888)     // 128 x 288
#define SBQKV  (SW0+202752)     // 384 x 96
#define SBOUT  (SW0+239616)     // 128 x 192  ends SW0+264192
#define SXB    3148800     // xb   [8192][88]  dead after conv1
#define SXCAT  3869696     // XCAT [8192][264] dead after mp
#define SX2    6032384     // X2   [8192][88]  dead after mp
#define ST3B   6753280     // T3B  [8192][88]  dead after conv5
#define SX3    7474176     // X3   [8192][88]  dead after mp
#define SMPB   8195072     // MPb  [8192][88]  dead after qkv  ends 8915968
// overlays (written after their hosts die):
#define SQB    3869696     // Qb  [16][2048][32]  (over XCAT)
#define SKB    4918272     // Kb  [16][2048][32]  (over XCAT)
#define SCDT   5966848     // CDT [16][16][2048]  (over XCAT tail + X2)
#define SXOB   6753280     // XOb [8192][112]     (over T3B + X3 head)

__constant__ float c_dlo[8] = {-0.010597401784997278f, 0.032883011666982945f,
    0.030841381835986965f, -0.18703481171888114f, -0.02798376941698385f,
    0.6308807679295904f, 0.7148465705525415f, 0.23037781330885523f};
__constant__ float c_dhi[8] = {-0.23037781330885523f, 0.7148465705525415f,
    -0.6308807679295904f, -0.02798376941698385f, 0.18703481171888114f,
    0.030841381835986965f, -0.032883011666982945f, -0.010597401784997278f};

__device__ __forceinline__ u16 f2bf(float f) {
    uint u = __float_as_uint(f);
    uint r = u + 0x7fffu + ((u >> 16) & 1u);
    return (u16)(r >> 16);
}

// ---------------- weight prep + x->bf16 ----------------------------------
__global__ __launch_bounds__(256) void prepk(
    const float* __restrict__ x,
    const float* __restrict__ w1, const float* __restrict__ w2a, const float* __restrict__ w2b,
    const float* __restrict__ w3a, const float* __restrict__ w3b, const float* __restrict__ w3c,
    const float* __restrict__ g1, const float* __restrict__ g2a, const float* __restrict__ g2b,
    const float* __restrict__ g3a, const float* __restrict__ g3b, const float* __restrict__ g3c,
    const float* __restrict__ b1, const float* __restrict__ b2a, const float* __restrict__ b3a,
    const float* __restrict__ Wmp, const float* __restrict__ Wq, const float* __restrict__ Wk,
    const float* __restrict__ Wv, const float* __restrict__ Wout, float* __restrict__ ws)
{
    u16* wu = (u16*)ws;
    int r = blockIdx.x * 256 + threadIdx.x;
    if (r < 264) {
        ws[OFF_BCAT + r] = (r < 88) ? b1[r] : (r < 176 ? b2a[r-88] : b3a[r-176]);
        return;
    }
    r -= 264;
    if (r < 320*96) {                       // WB1: cat(w1,w2a,w3a) folded
        int n = r / 96, kk = r % 96; float v = 0.f;
        if (kk < 88 && n < 264) {
            if (n < 88)       v = w1 [n*88+kk]       * g1 [n];
            else if (n < 176) v = w2a[(n-88)*88+kk]  * g2a[n-88];
            else              v = w3a[(n-176)*88+kk] * g3a[n-176];
            v *= BN_INV;
        }
        wu[SB1 + r] = f2bf(v); return;
    }
    r -= 320*96;
    if (r < 128*288) {                      // WB2B
        int n = r / 288, kk = r % 288, t = kk/96, i = kk%96; float v = 0.f;
        if (n < 88 && i < 88) v = w2b[n*264 + i*3 + t] * g2b[n] * BN_INV;
        wu[SB2B + r] = f2bf(v); return;
    }
    r -= 128*288;
    if (r < 128*288) {                      // WB3B
        int n = r / 288, kk = r % 288, t = kk/96, i = kk%96; float v = 0.f;
        if (n < 88 && i < 88) v = w3b[n*264 + i*3 + t] * g3b[n] * BN_INV;
        wu[SB3B + r] = f2bf(v); return;
    }
    r -= 128*288;
    if (r < 128*480) {                      // WB3C
        int n = r / 480, kk = r % 480, t = kk/96, i = kk%96; float v = 0.f;
        if (n < 88 && i < 88) v = w3c[n*440 + i*5 + t] * g3c[n] * BN_INV;
        wu[SB3C + r] = f2bf(v); return;
    }
    r -= 128*480;
    if (r < 128*288) {                      // WBMP
        int n = r / 288, kk = r % 288, c = kk/96, i = kk%96; float v = 0.f;
        if (n < 88 && i < 88) v = Wmp[n*264 + c*88 + i];
        wu[SBMP + r] = f2bf(v); return;
    }
    r -= 128*288;
    if (r < 384*96) {                       // WBQKV (q-scale folded)
        int n = r / 96, kk = r % 96, sec = n / 128, o = n % 128; float v = 0.f;
        if (o < 88 && kk < 88) {
            if (sec == 0)      v = Wq[o*88+kk] * QSCALE;
            else if (sec == 1) v = Wk[o*88+kk];
            else               v = Wv[o*88+kk];
        }
        wu[SBQKV + r] = f2bf(v); return;
    }
    r -= 384*96;
    if (r < 128*192) {                      // WBOUT
        int n = r / 192, kk = r % 192; float v = 0.f;
        if (n < 88 && kk < 112) v = Wout[n*112 + kk];
        wu[SBOUT + r] = f2bf(v); return;
    }
    r -= 128*192;
    if (r < 8192*88) {                      // xb
        wu[SXB + r] = f2bf(x[r]); return;
    }
}

// ---------------- generic bf16 MFMA GEMM, 64x64 tile, K-chunks of 96 ------
struct GemmChunks {
    int soff[5];    // short offset of bf16 source base
    int stride[5];  // in shorts
    int shift[5];   // row shift (halo)
    int cols[5];    // valid cols
};

// MODE 0: normal; MODE 1: qkv scatter; MODE 2: dual conv3 (nb>>1 selects set)
// OUTM bit0: write bf16 outb; bit1: write fp32 outf
template<int NCH, int MODE, int OUTM>
__global__ __launch_bounds__(256) void gemmk(GemmChunks ch,
    const u16* __restrict__ wsrc,
    const u16* __restrict__ Bw, const u16* __restrict__ Bw2, int Ktot,
    const float* __restrict__ bias, const float* __restrict__ bias2,
    const float* __restrict__ resid, int relu,
    u16* __restrict__ outb, u16* __restrict__ outb2,
    float* __restrict__ outf, int outStride, int N)
{
    __shared__ u16 As[64*104];
    __shared__ u16 Bs[64*104];
    int tid = threadIdx.x;
    int lane = tid & 63, w = tid >> 6, wr = w >> 1, wc = w & 1;
    int p0 = blockIdx.x * 64;
    int nb = blockIdx.y;
    int which = (MODE == 2) ? (nb >> 1) : 0;
    int nbl   = (MODE == 2) ? (nb & 1) : nb;
    const u16* Bw_ = (MODE == 2 && which) ? Bw2 : Bw;
    int bs = p0 & ~2047, be = bs + 2048;

    f32x4 acc[2][2];
    #pragma unroll
    for (int a = 0; a < 2; a++)
        #pragma unroll
        for (int b = 0; b < 2; b++) acc[a][b] = (f32x4){0.f,0.f,0.f,0.f};

    int ar0 = (wr*32 + (lane&15))*104 + (lane>>4)*8;
    int br0 = (wc*32 + (lane&15))*104 + (lane>>4)*8;

    for (int c = 0; c < NCH; c++) {
        int soff = ch.soff[c] + which*88;
        int stride = ch.stride[c], shift = ch.shift[c], cols = ch.cols[c];
        __syncthreads();
        // stage A: 64 rows x 96 shorts, pure vector copy
        for (int e = tid; e < 768; e += 256) {
            int r = e / 12, seg = e % 12;
            int row = p0 + r + shift;
            int4 val = {0,0,0,0};
            if (row >= bs && row < be && seg*8 < cols)
                val = *(const int4*)&wsrc[(size_t)soff + (size_t)row*stride + seg*8];
            *(int4*)&As[r*104 + seg*8] = val;
        }
        // stage B: 64 n-rows x 96 shorts
        for (int e = tid; e < 768; e += 256) {
            int n = e / 12, seg = e % 12;
            *(int4*)&Bs[n*104 + seg*8] =
                *(const int4*)&Bw_[((size_t)(nbl*64 + n))*Ktot + c*96 + seg*8];
        }
        __syncthreads();
        #pragma unroll
        for (int ks = 0; ks < 3; ks++) {
            s16x8 a0 = *(const s16x8*)&As[ar0 + ks*32];
            s16x8 a1 = *(const s16x8*)&As[ar0 + 16*104 + ks*32];
            s16x8 b0 = *(const s16x8*)&Bs[br0 + ks*32];
            s16x8 b1 = *(const s16x8*)&Bs[br0 + 16*104 + ks*32];
            acc[0][0] = __builtin_amdgcn_mfma_f32_16x16x32_bf16(a0, b0, acc[0][0], 0, 0, 0);
            acc[0][1] = __builtin_amdgcn_mfma_f32_16x16x32_bf16(a0, b1, acc[0][1], 0, 0, 0);
            acc[1][0] = __builtin_amdgcn_mfma_f32_16x16x32_bf16(a1, b0, acc[1][0], 0, 0, 0);
            acc[1][1] = __builtin_amdgcn_mfma_f32_16x16x32_bf16(a1, b1, acc[1][1], 0, 0, 0);
        }
    }

    int rbase = p0 + wr*32 + (lane>>4)*4;
    if (MODE != 1) {
        u16* outb_ = (MODE == 2 && which) ? outb2 : outb;
        const float* bias_ = (MODE == 2 && which) ? bias2 : bias;
        int cbase = nbl*64 + wc*32 + (lane&15);
        #pragma unroll
        for (int fn = 0; fn < 2; fn++) {
            int col = cbase + fn*16;
            if (col < N) {
                float bb = bias_ ? bias_[col] : 0.f;
                #pragma unroll
                for (int fm = 0; fm < 2; fm++)
                    #pragma unroll
                    for (int j = 0; j < 4; j++) {
                        int row = rbase + fm*16 + j;
                        float v = acc[fm][fn][j] + bb;
                        if (relu) v = fmaxf(v, 0.f);
                        if (resid) v += resid[(size_t)row*outStride + col];
                        if (OUTM & 1) outb_[(size_t)row*outStride + col] = f2bf(v);
                        if (OUTM & 2) outf[(size_t)row*outStride + col] = v;
                    }
            }
        }
    } else {
        u16* wq = outb;    // wu base
        int sec = nb >> 1;
        #pragma unroll
        for (int fn = 0; fn < 2; fn++) {
            int cw = (nb&1)*64 + wc*32 + fn*16 + (lane&15);
            if (cw < 88) {
                int h = cw / 22, d = cw % 22;
                #pragma unroll
                for (int fm = 0; fm < 2; fm++)
                    #pragma unroll
                    for (int j = 0; j < 4; j++) {
                        int row = rbase + fm*16 + j;
                        int b = row >> 11, s = row & 2047;
                        float v = acc[fm][fn][j];
                        if (sec == 0)
                            wq[SQB + ((size_t)(b*4+h)*2048 + s)*32 + d] = f2bf(v);
                        else if (sec == 1)
                            wq[SKB + ((size_t)(b*4+h)*2048 + s)*32 + d] = f2bf(v);
                        else
                            outf[OFF_V + (size_t)row*88 + cw] = v;
                    }
            }
        }
    }
}

// ---------------- DWT(V) -> CDT bf16 + cA scatter + pad zeroing -----------
__global__ __launch_bounds__(256) void dwtk(float* __restrict__ ws)
{
    u16* wu = (u16*)ws;
    int tid = threadIdx.x;
    int p0 = blockIdx.x * 16;
    const float* V = ws + OFF_V;
    for (int e = tid; e < 896; e += 256) {
        int p = e / 56, rr = e % 56, h = rr / 14, jj = rr % 14;
        int pos = p0 + p, b = pos >> 11, s = pos & 2047;
        const float* v = &V[(size_t)pos*88 + h*22];
        float ca = 0.f, cd = 0.f;
        #pragma unroll
        for (int t = 0; t < 8; t++) {
            int pp = 1 + 2*jj + t;
            int oi = pp < 7 ? 6 - pp : (pp < 29 ? pp - 7 : 50 - pp);
            float vv = v[oi];
            ca = fmaf(vv, c_dlo[7-t], ca);
            cd = fmaf(vv, c_dhi[7-t], cd);
        }
        wu[SCDT + ((size_t)((b*4+h)*16 + jj))*2048 + s] = f2bf(cd);
        int hs = h*2048 + s, s2 = hs >> 2, qd = hs & 3;
        wu[SXOB + ((size_t)b*2048 + s2)*112 + 56 + qd*14 + jj] = f2bf(ca);
    }
    // zero Qb/Kb pads d=22..31 (uints 11..15 of each 16-uint row)
    uint* wi = (uint*)ws;
    for (int e = tid; e < 640; e += 256) {
        int p = e / 40, t = e % 40;
        int h = t / 10, rest = t % 10, arr = rest / 5, ui = rest % 5;
        int pos = p0 + p, b = pos >> 11, s = pos & 2047;
        size_t base = (size_t)((arr ? SKB : SQB) >> 1) + ((size_t)(b*4+h)*2048 + s)*16;
        wi[base + 11 + ui] = 0;
    }
    // zero CDT rows d=14,15
    for (int e = tid; e < 128; e += 256) {
        int p = e / 8, t = e % 8, h = t >> 1, dd = 14 + (t & 1);
        int pos = p0 + p, b = pos >> 11, s = pos & 2047;
        wu[SCDT + ((size_t)((b*4+h)*16 + dd))*2048 + s] = 0;
    }
}

// ---------------- MFMA flash attention, 128-key tiles ---------------------
// 256 thr = 4 waves; grid (32 q-tiles, 16 bh). Wave w owns 16 q-rows.
__global__ __launch_bounds__(256) void attnk(float* __restrict__ ws)
{
    const u16* wu = (const u16*)ws;
    u16* wua = (u16*)ws;
    __shared__ __align__(16) u16 Kt[128*40];       // 128 keys x 32d pad 40
    __shared__ __align__(16) u16 CDt[16*136];      // 16 d x 128 keys pad 136
    __shared__ __align__(16) u16 Pb[4][16*136];    // per-wave P [q16][key128]
    __shared__ float cb[4][16];
    __shared__ float lb[4][16];
    int tid = threadIdx.x, lane = tid & 63, w = tid >> 6;
    int bh = blockIdx.y;
    int q0 = blockIdx.x * 64 + w * 16;
    int qrow = lane & 15, grp = lane >> 4;

    s16x8 qf = *(const s16x8*)&wu[SQB + ((size_t)bh*2048 + q0 + qrow)*32 + grp*8];
    const u16* Kbase = wu + SKB + (size_t)bh*2048*32;
    const u16* Cbase = wu + SCDT + (size_t)bh*16*2048;

    f32x4 o = (f32x4){0.f,0.f,0.f,0.f};
    float m = -1e30f, l = 0.f;

    for (int kt = 0; kt < 16; kt++) {
        __syncthreads();
        for (int e = tid; e < 512; e += 256) {     // K tile: 128x32
            int r = e >> 2, seg = e & 3;
            *(int4*)&Kt[r*40 + seg*8] = *(const int4*)&Kbase[(size_t)(kt*128 + r)*32 + seg*8];
        }
        {   // cD^T tile: 16 d x 128 keys (exactly 256 int4)
            int d = tid >> 4, seg = tid & 15;
            *(int4*)&CDt[d*136 + seg*8] = *(const int4*)&Cbase[(size_t)d*2048 + kt*128 + seg*8];
        }
        __syncthreads();

        f32x4 s4[8];
        #pragma unroll
        for (int sub = 0; sub < 8; sub++) {
            s16x8 kf = *(const s16x8*)&Kt[(sub*16 + qrow)*40 + grp*8];
            s4[sub] = __builtin_amdgcn_mfma_f32_16x16x32_bf16(kf, qf,
                        (f32x4){0.f,0.f,0.f,0.f}, 0, 0, 0);
        }
        float sv[32];
        #pragma unroll
        for (int sub = 0; sub < 8; sub++)
            #pragma unroll
            for (int j = 0; j < 4; j++) sv[sub*4+j] = s4[sub][j];

        // tree max over 32
        float mx[16];
        #pragma unroll
        for (int i = 0; i < 16; i++) mx[i] = fmaxf(sv[i], sv[i+16]);
        #pragma unroll
        for (int i = 0; i < 8; i++) mx[i] = fmaxf(mx[i], mx[i+8]);
        #pragma unroll
        for (int i = 0; i < 4; i++) mx[i] = fmaxf(mx[i], mx[i+4]);
        float tm = fmaxf(fmaxf(mx[0], mx[1]), fmaxf(mx[2], mx[3]));
        tm = fmaxf(tm, __shfl_xor(tm, 16));
        tm = fmaxf(tm, __shfl_xor(tm, 32));
        float mn = fmaxf(m, tm);
        float corr = __expf(m - mn);
        m = mn;

        float pv[32];
        #pragma unroll
        for (int i = 0; i < 32; i++) pv[i] = __expf(sv[i] - mn);
        float sm[16];
        #pragma unroll
        for (int i = 0; i < 16; i++) sm[i] = pv[i] + pv[i+16];
        #pragma unroll
        for (int i = 0; i < 8; i++) sm[i] += sm[i+8];
        #pragma unroll
        for (int i = 0; i < 4; i++) sm[i] += sm[i+4];
        float ls = (sm[0] + sm[1]) + (sm[2] + sm[3]);
        ls += __shfl_xor(ls, 16);
        ls += __shfl_xor(ls, 32);
        l = l * corr + ls;

        if (lane < 16) cb[w][lane] = corr;
        __builtin_amdgcn_s_waitcnt(0);
        {
            const float* cp = &cb[w][grp*4];
            #pragma unroll
            for (int j = 0; j < 4; j++) o[j] *= cp[j];
        }
        // pack P -> per-wave LDS
        {
            uint* pb32 = (uint*)Pb[w];
            #pragma unroll
            for (int sub = 0; sub < 8; sub++) {
                uint u01 = (uint)f2bf(pv[sub*4+0]) | ((uint)f2bf(pv[sub*4+1]) << 16);
                uint u23 = (uint)f2bf(pv[sub*4+2]) | ((uint)f2bf(pv[sub*4+3]) << 16);
                int sa = qrow*136 + sub*16 + grp*4;
                pb32[sa >> 1] = u01;
                pb32[(sa >> 1) + 1] = u23;
            }
        }
        // PV: O[q][d] += P[q][k] * cD^T[d][k]
        #pragma unroll
        for (int ks = 0; ks < 4; ks++) {
            s16x8 pa = *(const s16x8*)&Pb[w][qrow*136 + ks*32 + grp*8];
            s16x8 cf = *(const s16x8*)&CDt[qrow*136 + ks*32 + grp*8];
            o = __builtin_amdgcn_mfma_f32_16x16x32_bf16(pa, cf, o, 0, 0, 0);
        }
    }

    if (lane < 16) lb[w][lane] = l;
    __builtin_amdgcn_s_waitcnt(0);
    {
        const float* lp = &lb[w][grp*4];
        int b = bh >> 2, h = bh & 3, d = qrow;
        if (d < 14) {
            #pragma unroll
            for (int j = 0; j < 4; j++) {
                int s = q0 + grp*4 + j;
                float val = o[j] / lp[j];
                wua[SXOB + ((size_t)b*2048 + s)*112 + h*14 + d] = f2bf(fmaxf(val, 0.f));
            }
        }
    }
}

extern "C" void kernel_launch(void* const* d_in, const int* in_sizes, int n_in,
                              void* d_out, int out_size, void* d_ws, size_t ws_size,
                              hipStream_t stream) {
    const float* x    = (const float*)d_in[0];
    const float* w1   = (const float*)d_in[1];
    const float* w2a  = (const float*)d_in[2];
    const float* w2b  = (const float*)d_in[3];
    const float* w3a  = (const float*)d_in[4];
    const float* w3b  = (const float*)d_in[5];
    const float* w3c  = (const float*)d_in[6];
    const float* g1   = (const float*)d_in[7];
    const float* g2a  = (const float*)d_in[8];
    const float* g2b  = (const float*)d_in[9];
    const float* g3a  = (const float*)d_in[10];
    const float* g3b  = (const float*)d_in[11];
    const float* g3c  = (const float*)d_in[12];
    const float* b1   = (const float*)d_in[13];
    const float* b2a  = (const float*)d_in[14];
    const float* b2b  = (const float*)d_in[15];
    const float* b3a  = (const float*)d_in[16];
    const float* b3b  = (const float*)d_in[17];
    const float* b3c  = (const float*)d_in[18];
    const float* Wmp  = (const float*)d_in[19];
    const float* bmp  = (const float*)d_in[20];
    const float* Wq   = (const float*)d_in[21];
    const float* Wk   = (const float*)d_in[22];
    const float* Wv   = (const float*)d_in[23];
    const float* Wout = (const float*)d_in[24];
    const float* bout = (const float*)d_in[25];
    float* ws = (float*)d_ws;
    float* out = (float*)d_out;
    u16* wu = (u16*)d_ws;

    prepk<<<3850, 256, 0, stream>>>(x, w1, w2a, w2b, w3a, w3b, w3c,
                                    g1, g2a, g2b, g3a, g3b, g3c,
                                    b1, b2a, b3a, Wmp, Wq, Wk, Wv, Wout, ws);

    {   // conv1: xb @ WB1 -> XCATb, bias BCAT, relu
        GemmChunks c{}; c.soff[0]=SXB; c.stride[0]=88; c.shift[0]=0; c.cols[0]=88;
        gemmk<1,0,1><<<dim3(128,5), 256, 0, stream>>>(c, wu, wu+SB1, nullptr, 96,
            ws+OFF_BCAT, nullptr, nullptr, 1, wu+SXCAT, nullptr, nullptr, 264, 264);
    }
    {   // conv3a + conv3b fused
        GemmChunks c{};
        for (int t = 0; t < 3; t++) { c.soff[t]=SXCAT+88; c.stride[t]=264; c.shift[t]=t-1; c.cols[t]=88; }
        gemmk<3,2,1><<<dim3(128,4), 256, 0, stream>>>(c, wu, wu+SB2B, wu+SB3B, 288,
            b2b, b3b, nullptr, 1, wu+SX2, wu+ST3B, nullptr, 88, 88);
    }
    {   // conv5: T3Bb @ WB3C -> X3b
        GemmChunks c{};
        for (int t = 0; t < 5; t++) { c.soff[t]=ST3B; c.stride[t]=88; c.shift[t]=t-2; c.cols[t]=88; }
        gemmk<5,0,1><<<dim3(128,2), 256, 0, stream>>>(c, wu, wu+SB3C, nullptr, 480,
            b3c, nullptr, nullptr, 1, wu+SX3, nullptr, nullptr, 88, 88);
    }
    {   // mp: cat @ WBMP + bmp + x -> MPb (bf16) + MP (fp32)
        GemmChunks c{};
        c.soff[0]=SXCAT; c.stride[0]=264; c.shift[0]=0; c.cols[0]=88;
        c.soff[1]=SX2;   c.stride[1]=88;  c.shift[1]=0; c.cols[1]=88;
        c.soff[2]=SX3;   c.stride[2]=88;  c.shift[2]=0; c.cols[2]=88;
        gemmk<3,0,3><<<dim3(128,2), 256, 0, stream>>>(c, wu, wu+SBMP, nullptr, 288,
            bmp, nullptr, x, 0, wu+SMPB, nullptr, ws+OFF_MP, 88, 88);
    }
    {   // qkv: MPb @ WBQKV -> Qb/Kb bf16 + V fp32
        GemmChunks c{}; c.soff[0]=SMPB; c.stride[0]=88; c.shift[0]=0; c.cols[0]=88;
        gemmk<1,1,0><<<dim3(128,6), 256, 0, stream>>>(c, wu, wu+SBQKV, nullptr, 96,
            nullptr, nullptr, nullptr, 0, wu, nullptr, ws, 0, 0);
    }
    dwtk<<<512, 256, 0, stream>>>(ws);
    attnk<<<dim3(32, 16), 256, 0, stream>>>(ws);
    {   // final: XOb @ WBOUT + bout + MP -> out
        GemmChunks c{};
        c.soff[0]=SXOB;    c.stride[0]=112; c.shift[0]=0; c.cols[0]=96;
        c.soff[1]=SXOB+96; c.stride[1]=112; c.shift[1]=0; c.cols[1]=16;
        gemmk<2,0,2><<<dim3(128,2), 256, 0, stream>>>(c, wu, wu+SBOUT, nullptr, 192,
            bout, nullptr, ws+OFF_MP, 0, nullptr, nullptr, out, 88, 88);
    }
}

// Round 7
// 202.883 us; speedup vs baseline: 5.2006x; 1.0369x over previous
//
#include <hip/hip_runtime.h>

#define BN_INV  0.99999500003749981f
#define QSCALE  0.21320071635561041f   // 22^-0.5

typedef unsigned int uint;
typedef unsigned short u16;
typedef __attribute__((ext_vector_type(8))) short s16x8;
typedef __attribute__((ext_vector_type(4))) float f32x4;

// ---- ws layout ----
// float offsets:
#define OFF_BCAT 0         // 264
#define OFF_V    512       // 8192*88 fp32 (qkv out, dwt in)
#define OFF_MP   721408    // 8192*88 fp32 (final residual)   ends 1442304 fl
// short offsets (shorts region starts at 2884608 sh):
#define SW0    2884608
#define SB1    (SW0)            // 320 x 96
#define SB2B   (SW0+30720)      // 128 x 288
#define SB3B   (SW0+67584)      // 128 x 288
#define SB3C   (SW0+104448)     // 128 x 480
#define SBMP   (SW0+165888)     // 128 x 288
#define SBQKV  (SW0+202752)     // 384 x 96
#define SBOUT  (SW0+239616)     // 128 x 192  ends SW0+264192
#define SXB    3148800     // xb   [8192][88]  dead after conv1
#define SXCAT  3869696     // XCAT [8192][264] dead after mp
#define SX2    6032384     // X2   [8192][88]  dead after mp
#define ST3B   6753280     // T3B  [8192][88]  dead after conv5
#define SX3    7474176     // X3   [8192][88]  dead after mp
#define SMPB   8195072     // MPb  [8192][88]  dead after qkv  ends 8915968
// overlays (written after their hosts die):
#define SQB    3869696     // Qb  [16][2048][32]  (over XCAT)
#define SKB    4918272     // Kb  [16][2048][32]  (over XCAT)
#define SCDT   5966848     // CDT [16][16][2048]  (over XCAT tail + X2)
#define SXOB   6753280     // XOb [8192][112]     (over T3B + X3 head)

__constant__ float c_dlo[8] = {-0.010597401784997278f, 0.032883011666982945f,
    0.030841381835986965f, -0.18703481171888114f, -0.02798376941698385f,
    0.6308807679295904f, 0.7148465705525415f, 0.23037781330885523f};
__constant__ float c_dhi[8] = {-0.23037781330885523f, 0.7148465705525415f,
    -0.6308807679295904f, -0.02798376941698385f, 0.18703481171888114f,
    0.030841381835986965f, -0.032883011666982945f, -0.010597401784997278f};

__device__ __forceinline__ u16 f2bf(float f) {
    uint u = __float_as_uint(f);
    uint r = u + 0x7fffu + ((u >> 16) & 1u);
    return (u16)(r >> 16);
}

// ---------------- weight prep + x->bf16 ----------------------------------
__global__ __launch_bounds__(256) void prepk(
    const float* __restrict__ x,
    const float* __restrict__ w1, const float* __restrict__ w2a, const float* __restrict__ w2b,
    const float* __restrict__ w3a, const float* __restrict__ w3b, const float* __restrict__ w3c,
    const float* __restrict__ g1, const float* __restrict__ g2a, const float* __restrict__ g2b,
    const float* __restrict__ g3a, const float* __restrict__ g3b, const float* __restrict__ g3c,
    const float* __restrict__ b1, const float* __restrict__ b2a, const float* __restrict__ b3a,
    const float* __restrict__ Wmp, const float* __restrict__ Wq, const float* __restrict__ Wk,
    const float* __restrict__ Wv, const float* __restrict__ Wout, float* __restrict__ ws)
{
    u16* wu = (u16*)ws;
    int r = blockIdx.x * 256 + threadIdx.x;
    if (r < 264) {
        ws[OFF_BCAT + r] = (r < 88) ? b1[r] : (r < 176 ? b2a[r-88] : b3a[r-176]);
        return;
    }
    r -= 264;
    if (r < 320*96) {                       // WB1: cat(w1,w2a,w3a) folded
        int n = r / 96, kk = r % 96; float v = 0.f;
        if (kk < 88 && n < 264) {
            if (n < 88)       v = w1 [n*88+kk]       * g1 [n];
            else if (n < 176) v = w2a[(n-88)*88+kk]  * g2a[n-88];
            else              v = w3a[(n-176)*88+kk] * g3a[n-176];
            v *= BN_INV;
        }
        wu[SB1 + r] = f2bf(v); return;
    }
    r -= 320*96;
    if (r < 128*288) {                      // WB2B
        int n = r / 288, kk = r % 288, t = kk/96, i = kk%96; float v = 0.f;
        if (n < 88 && i < 88) v = w2b[n*264 + i*3 + t] * g2b[n] * BN_INV;
        wu[SB2B + r] = f2bf(v); return;
    }
    r -= 128*288;
    if (r < 128*288) {                      // WB3B
        int n = r / 288, kk = r % 288, t = kk/96, i = kk%96; float v = 0.f;
        if (n < 88 && i < 88) v = w3b[n*264 + i*3 + t] * g3b[n] * BN_INV;
        wu[SB3B + r] = f2bf(v); return;
    }
    r -= 128*288;
    if (r < 128*480) {                      // WB3C
        int n = r / 480, kk = r % 480, t = kk/96, i = kk%96; float v = 0.f;
        if (n < 88 && i < 88) v = w3c[n*440 + i*5 + t] * g3c[n] * BN_INV;
        wu[SB3C + r] = f2bf(v); return;
    }
    r -= 128*480;
    if (r < 128*288) {                      // WBMP
        int n = r / 288, kk = r % 288, c = kk/96, i = kk%96; float v = 0.f;
        if (n < 88 && i < 88) v = Wmp[n*264 + c*88 + i];
        wu[SBMP + r] = f2bf(v); return;
    }
    r -= 128*288;
    if (r < 384*96) {                       // WBQKV (q-scale folded)
        int n = r / 96, kk = r % 96, sec = n / 128, o = n % 128; float v = 0.f;
        if (o < 88 && kk < 88) {
            if (sec == 0)      v = Wq[o*88+kk] * QSCALE;
            else if (sec == 1) v = Wk[o*88+kk];
            else               v = Wv[o*88+kk];
        }
        wu[SBQKV + r] = f2bf(v); return;
    }
    r -= 384*96;
    if (r < 128*192) {                      // WBOUT
        int n = r / 192, kk = r % 192; float v = 0.f;
        if (n < 88 && kk < 112) v = Wout[n*112 + kk];
        wu[SBOUT + r] = f2bf(v); return;
    }
    r -= 128*192;
    if (r < 8192*88) {                      // xb
        wu[SXB + r] = f2bf(x[r]); return;
    }
}

// ---------------- generic bf16 MFMA GEMM, 64x64 tile, K-chunks of 96 ------
struct GemmChunks {
    int soff[5];    // short offset of bf16 source base
    int stride[5];  // in shorts
    int shift[5];   // row shift (halo)
    int cols[5];    // valid cols
};

// MODE 0: normal; MODE 1: qkv scatter; MODE 2: dual conv3 (nb>>1 selects set)
// OUTM bit0: write bf16 outb; bit1: write fp32 outf
template<int NCH, int MODE, int OUTM>
__global__ __launch_bounds__(256) void gemmk(GemmChunks ch,
    const u16* __restrict__ wsrc,
    const u16* __restrict__ Bw, const u16* __restrict__ Bw2, int Ktot,
    const float* __restrict__ bias, const float* __restrict__ bias2,
    const float* __restrict__ resid, int relu,
    u16* __restrict__ outb, u16* __restrict__ outb2,
    float* __restrict__ outf, int outStride, int N)
{
    __shared__ u16 As[64*104];
    __shared__ u16 Bs[64*104];
    int tid = threadIdx.x;
    int lane = tid & 63, w = tid >> 6, wr = w >> 1, wc = w & 1;
    int p0 = blockIdx.x * 64;
    int nb = blockIdx.y;
    int which = (MODE == 2) ? (nb >> 1) : 0;
    int nbl   = (MODE == 2) ? (nb & 1) : nb;
    const u16* Bw_ = (MODE == 2 && which) ? Bw2 : Bw;
    int bs = p0 & ~2047, be = bs + 2048;

    f32x4 acc[2][2];
    #pragma unroll
    for (int a = 0; a < 2; a++)
        #pragma unroll
        for (int b = 0; b < 2; b++) acc[a][b] = (f32x4){0.f,0.f,0.f,0.f};

    int ar0 = (wr*32 + (lane&15))*104 + (lane>>4)*8;
    int br0 = (wc*32 + (lane&15))*104 + (lane>>4)*8;

    int4 ra[3], rb[3];
    auto loadC = [&](int c) {
        int soff = ch.soff[c] + which*88;
        int stride = ch.stride[c], shift = ch.shift[c], cols = ch.cols[c];
        #pragma unroll
        for (int t = 0; t < 3; t++) {
            int e = tid + t*256;
            int r = e / 12, seg = e % 12;
            int row = p0 + r + shift;
            int4 v = {0,0,0,0};
            if (row >= bs && row < be && seg*8 < cols)
                v = *(const int4*)&wsrc[(size_t)soff + (size_t)row*stride + seg*8];
            ra[t] = v;
            rb[t] = *(const int4*)&Bw_[((size_t)(nbl*64 + r))*Ktot + c*96 + seg*8];
        }
    };

    loadC(0);
    for (int c = 0; c < NCH; c++) {
        #pragma unroll
        for (int t = 0; t < 3; t++) {
            int e = tid + t*256;
            int r = e / 12, seg = e % 12;
            *(int4*)&As[r*104 + seg*8] = ra[t];
            *(int4*)&Bs[r*104 + seg*8] = rb[t];
        }
        __syncthreads();
        if (c + 1 < NCH) loadC(c + 1);      // prefetch flies under MFMA
        #pragma unroll
        for (int ks = 0; ks < 3; ks++) {
            s16x8 a0 = *(const s16x8*)&As[ar0 + ks*32];
            s16x8 a1 = *(const s16x8*)&As[ar0 + 16*104 + ks*32];
            s16x8 b0 = *(const s16x8*)&Bs[br0 + ks*32];
            s16x8 b1 = *(const s16x8*)&Bs[br0 + 16*104 + ks*32];
            acc[0][0] = __builtin_amdgcn_mfma_f32_16x16x32_bf16(a0, b0, acc[0][0], 0, 0, 0);
            acc[0][1] = __builtin_amdgcn_mfma_f32_16x16x32_bf16(a0, b1, acc[0][1], 0, 0, 0);
            acc[1][0] = __builtin_amdgcn_mfma_f32_16x16x32_bf16(a1, b0, acc[1][0], 0, 0, 0);
            acc[1][1] = __builtin_amdgcn_mfma_f32_16x16x32_bf16(a1, b1, acc[1][1], 0, 0, 0);
        }
        __syncthreads();
    }

    int rbase = p0 + wr*32 + (lane>>4)*4;
    if (MODE != 1) {
        u16* outb_ = (MODE == 2 && which) ? outb2 : outb;
        const float* bias_ = (MODE == 2 && which) ? bias2 : bias;
        int cbase = nbl*64 + wc*32 + (lane&15);
        #pragma unroll
        for (int fn = 0; fn < 2; fn++) {
            int col = cbase + fn*16;
            if (col < N) {
                float bb = bias_ ? bias_[col] : 0.f;
                #pragma unroll
                for (int fm = 0; fm < 2; fm++)
                    #pragma unroll
                    for (int j = 0; j < 4; j++) {
                        int row = rbase + fm*16 + j;
                        float v = acc[fm][fn][j] + bb;
                        if (relu) v = fmaxf(v, 0.f);
                        if (resid) v += resid[(size_t)row*outStride + col];
                        if (OUTM & 1) outb_[(size_t)row*outStride + col] = f2bf(v);
                        if (OUTM & 2) outf[(size_t)row*outStride + col] = v;
                    }
            }
        }
    } else {
        u16* wq = outb;    // wu base
        int sec = nb >> 1;
        #pragma unroll
        for (int fn = 0; fn < 2; fn++) {
            int cw = (nb&1)*64 + wc*32 + fn*16 + (lane&15);
            if (cw < 88) {
                int h = cw / 22, d = cw % 22;
                #pragma unroll
                for (int fm = 0; fm < 2; fm++)
                    #pragma unroll
                    for (int j = 0; j < 4; j++) {
                        int row = rbase + fm*16 + j;
                        int b = row >> 11, s = row & 2047;
                        float v = acc[fm][fn][j];
                        if (sec == 0)
                            wq[SQB + ((size_t)(b*4+h)*2048 + s)*32 + d] = f2bf(v);
                        else if (sec == 1)
                            wq[SKB + ((size_t)(b*4+h)*2048 + s)*32 + d] = f2bf(v);
                        else
                            outf[OFF_V + (size_t)row*88 + cw] = v;
                    }
            }
        }
    }
}

// ---------------- DWT(V) -> CDT bf16 + cA scatter + pad zeroing -----------
__global__ __launch_bounds__(256) void dwtk(float* __restrict__ ws)
{
    u16* wu = (u16*)ws;
    int tid = threadIdx.x;
    int p0 = blockIdx.x * 16;
    const float* V = ws + OFF_V;
    for (int e = tid; e < 896; e += 256) {
        int p = e / 56, rr = e % 56, h = rr / 14, jj = rr % 14;
        int pos = p0 + p, b = pos >> 11, s = pos & 2047;
        const float* v = &V[(size_t)pos*88 + h*22];
        float ca = 0.f, cd = 0.f;
        #pragma unroll
        for (int t = 0; t < 8; t++) {
            int pp = 1 + 2*jj + t;
            int oi = pp < 7 ? 6 - pp : (pp < 29 ? pp - 7 : 50 - pp);
            float vv = v[oi];
            ca = fmaf(vv, c_dlo[7-t], ca);
            cd = fmaf(vv, c_dhi[7-t], cd);
        }
        wu[SCDT + ((size_t)((b*4+h)*16 + jj))*2048 + s] = f2bf(cd);
        int hs = h*2048 + s, s2 = hs >> 2, qd = hs & 3;
        wu[SXOB + ((size_t)b*2048 + s2)*112 + 56 + qd*14 + jj] = f2bf(ca);
    }
    // zero Qb/Kb pads d=22..31 (uints 11..15 of each 16-uint row)
    uint* wi = (uint*)ws;
    for (int e = tid; e < 640; e += 256) {
        int p = e / 40, t = e % 40;
        int h = t / 10, rest = t % 10, arr = rest / 5, ui = rest % 5;
        int pos = p0 + p, b = pos >> 11, s = pos & 2047;
        size_t base = (size_t)((arr ? SKB : SQB) >> 1) + ((size_t)(b*4+h)*2048 + s)*16;
        wi[base + 11 + ui] = 0;
    }
    // zero CDT rows d=14,15
    for (int e = tid; e < 128; e += 256) {
        int p = e / 8, t = e % 8, h = t >> 1, dd = 14 + (t & 1);
        int pos = p0 + p, b = pos >> 11, s = pos & 2047;
        wu[SCDT + ((size_t)((b*4+h)*16 + dd))*2048 + s] = 0;
    }
}

// ---------------- MFMA flash attention, 8-wave split-K + defer-max --------
// 512 thr = 8 waves; grid (32 q-tiles, 16 bh). Wave w: q-sub (w&3), key-half
// (w>>2) of 1024 keys in 16 tiles of 64. Partials merged in LDS.
__global__ __launch_bounds__(512, 4) void attnk(float* __restrict__ ws)
{
    const u16* wu = (const u16*)ws;
    u16* wua = (u16*)ws;
    __shared__ __align__(16) u16 Kt[2*64*40];      // [half][key64][40]
    __shared__ __align__(16) u16 CDt[2*16*72];     // [half][d16][72]
    __shared__ __align__(16) u16 Pb[8][16*72];     // per-wave P
    __shared__ float cb[8][16];
    int tid = threadIdx.x, lane = tid & 63, w = tid >> 6;
    int bh = blockIdx.y;
    int qsub = w & 3, half = w >> 2;
    int q0 = blockIdx.x * 64 + qsub * 16;
    int qrow = lane & 15, grp = lane >> 4;

    s16x8 qf = *(const s16x8*)&wu[SQB + ((size_t)bh*2048 + q0 + qrow)*32 + grp*8];
    const u16* Kbase = wu + SKB + (size_t)bh*2048*32;
    const u16* Cbase = wu + SCDT + (size_t)bh*16*2048;
    const u16* Kh = &Kt[half*2560];
    const u16* Ch = &CDt[half*1152];

    f32x4 o = (f32x4){0.f,0.f,0.f,0.f};
    float m = -1e30f, l = 0.f;

    for (int kt = 0; kt < 16; kt++) {
        __syncthreads();
        {   // stage K: both halves, 512 int4
            int hh = tid >> 8, rr = (tid >> 2) & 63, seg = tid & 3;
            *(int4*)&Kt[hh*2560 + rr*40 + seg*8] =
                *(const int4*)&Kbase[(size_t)(hh*1024 + kt*64 + rr)*32 + seg*8];
        }
        if (tid < 256) {   // stage cD^T: both halves, 256 int4
            int hh = tid >> 7, d = (tid >> 3) & 15, seg = tid & 7;
            *(int4*)&CDt[hh*1152 + d*72 + seg*8] =
                *(const int4*)&Cbase[(size_t)d*2048 + hh*1024 + kt*64 + seg*8];
        }
        __syncthreads();

        f32x4 s4[4];
        #pragma unroll
        for (int sub = 0; sub < 4; sub++) {
            s16x8 kf = *(const s16x8*)&Kh[(sub*16 + qrow)*40 + grp*8];
            s4[sub] = __builtin_amdgcn_mfma_f32_16x16x32_bf16(kf, qf,
                        (f32x4){0.f,0.f,0.f,0.f}, 0, 0, 0);
        }
        float sv[16];
        #pragma unroll
        for (int sub = 0; sub < 4; sub++)
            #pragma unroll
            for (int j = 0; j < 4; j++) sv[sub*4+j] = s4[sub][j];

        float mx[8];
        #pragma unroll
        for (int i = 0; i < 8; i++) mx[i] = fmaxf(sv[i], sv[i+8]);
        #pragma unroll
        for (int i = 0; i < 4; i++) mx[i] = fmaxf(mx[i], mx[i+4]);
        float tm = fmaxf(fmaxf(mx[0], mx[1]), fmaxf(mx[2], mx[3]));
        tm = fmaxf(tm, __shfl_xor(tm, 16));
        tm = fmaxf(tm, __shfl_xor(tm, 32));

        if (!__all(tm <= m + 8.f)) {        // defer-max: rescale rarely
            float mn = fmaxf(m, tm);
            float corr = __expf(m - mn);
            m = mn; l *= corr;
            if (lane < 16) cb[w][lane] = corr;
            __builtin_amdgcn_s_waitcnt(0);
            const float* cp = &cb[w][grp*4];
            #pragma unroll
            for (int j = 0; j < 4; j++) o[j] *= cp[j];
        }

        float pv[16];
        #pragma unroll
        for (int i = 0; i < 16; i++) pv[i] = __expf(sv[i] - m);
        float sm[8];
        #pragma unroll
        for (int i = 0; i < 8; i++) sm[i] = pv[i] + pv[i+8];
        #pragma unroll
        for (int i = 0; i < 4; i++) sm[i] += sm[i+4];
        float ls = (sm[0] + sm[1]) + (sm[2] + sm[3]);
        ls += __shfl_xor(ls, 16);
        ls += __shfl_xor(ls, 32);
        l += ls;

        {   // pack P -> per-wave LDS
            uint* pb32 = (uint*)Pb[w];
            #pragma unroll
            for (int sub = 0; sub < 4; sub++) {
                uint u01 = (uint)f2bf(pv[sub*4+0]) | ((uint)f2bf(pv[sub*4+1]) << 16);
                uint u23 = (uint)f2bf(pv[sub*4+2]) | ((uint)f2bf(pv[sub*4+3]) << 16);
                int sa = qrow*72 + sub*16 + grp*4;
                *(uint2*)&pb32[sa >> 1] = make_uint2(u01, u23);
            }
        }
        #pragma unroll
        for (int ks = 0; ks < 2; ks++) {
            s16x8 pa = *(const s16x8*)&Pb[w][qrow*72 + ks*32 + grp*8];
            s16x8 cf = *(const s16x8*)&Ch[qrow*72 + ks*32 + grp*8];
            o = __builtin_amdgcn_mfma_f32_16x16x32_bf16(pa, cf, o, 0, 0, 0);
        }
    }

    // ---- merge halves via LDS partials (overlay Kt: 8*16*18 f32 = 9216 B)
    __syncthreads();
    float* part = (float*)Kt;
    if (lane < 16) { part[(w*16+lane)*18 + 0] = m; part[(w*16+lane)*18 + 1] = l; }
    #pragma unroll
    for (int j = 0; j < 4; j++) part[(w*16 + grp*4 + j)*18 + 2 + qrow] = o[j];
    __syncthreads();
    if (w < 4) {
        int q = qrow;
        const float* pa = &part[(w*16 + q)*18];
        const float* pb = &part[((w+4)*16 + q)*18];
        float m0 = pa[0], l0 = pa[1], m1 = pb[0], l1 = pb[1];
        float M = fmaxf(m0, m1);
        float e0 = __expf(m0 - M), e1 = __expf(m1 - M);
        float inv = 1.f / (l0*e0 + l1*e1);
        int b = bh >> 2, h = bh & 3;
        int s = blockIdx.x * 64 + w * 16 + q;
        #pragma unroll
        for (int dd = 0; dd < 4; dd++) {
            int d = grp*4 + dd;
            if (d < 14) {
                float val = (pa[2+d]*e0 + pb[2+d]*e1) * inv;
                wua[SXOB + ((size_t)b*2048 + s)*112 + h*14 + d] = f2bf(fmaxf(val, 0.f));
            }
        }
    }
}

extern "C" void kernel_launch(void* const* d_in, const int* in_sizes, int n_in,
                              void* d_out, int out_size, void* d_ws, size_t ws_size,
                              hipStream_t stream) {
    const float* x    = (const float*)d_in[0];
    const float* w1   = (const float*)d_in[1];
    const float* w2a  = (const float*)d_in[2];
    const float* w2b  = (const float*)d_in[3];
    const float* w3a  = (const float*)d_in[4];
    const float* w3b  = (const float*)d_in[5];
    const float* w3c  = (const float*)d_in[6];
    const float* g1   = (const float*)d_in[7];
    const float* g2a  = (const float*)d_in[8];
    const float* g2b  = (const float*)d_in[9];
    const float* g3a  = (const float*)d_in[10];
    const float* g3b  = (const float*)d_in[11];
    const float* g3c  = (const float*)d_in[12];
    const float* b1   = (const float*)d_in[13];
    const float* b2a  = (const float*)d_in[14];
    const float* b2b  = (const float*)d_in[15];
    const float* b3a  = (const float*)d_in[16];
    const float* b3b  = (const float*)d_in[17];
    const float* b3c  = (const float*)d_in[18];
    const float* Wmp  = (const float*)d_in[19];
    const float* bmp  = (const float*)d_in[20];
    const float* Wq   = (const float*)d_in[21];
    const float* Wk   = (const float*)d_in[22];
    const float* Wv   = (const float*)d_in[23];
    const float* Wout = (const float*)d_in[24];
    const float* bout = (const float*)d_in[25];
    float* ws = (float*)d_ws;
    float* out = (float*)d_out;
    u16* wu = (u16*)d_ws;

    prepk<<<3850, 256, 0, stream>>>(x, w1, w2a, w2b, w3a, w3b, w3c,
                                    g1, g2a, g2b, g3a, g3b, g3c,
                                    b1, b2a, b3a, Wmp, Wq, Wk, Wv, Wout, ws);

    {   // conv1: xb @ WB1 -> XCATb, bias BCAT, relu
        GemmChunks c{}; c.soff[0]=SXB; c.stride[0]=88; c.shift[0]=0; c.cols[0]=88;
        gemmk<1,0,1><<<dim3(128,5), 256, 0, stream>>>(c, wu, wu+SB1, nullptr, 96,
            ws+OFF_BCAT, nullptr, nullptr, 1, wu+SXCAT, nullptr, nullptr, 264, 264);
    }
    {   // conv3a + conv3b fused
        GemmChunks c{};
        for (int t = 0; t < 3; t++) { c.soff[t]=SXCAT+88; c.stride[t]=264; c.shift[t]=t-1; c.cols[t]=88; }
        gemmk<3,2,1><<<dim3(128,4), 256, 0, stream>>>(c, wu, wu+SB2B, wu+SB3B, 288,
            b2b, b3b, nullptr, 1, wu+SX2, wu+ST3B, nullptr, 88, 88);
    }
    {   // conv5: T3Bb @ WB3C -> X3b
        GemmChunks c{};
        for (int t = 0; t < 5; t++) { c.soff[t]=ST3B; c.stride[t]=88; c.shift[t]=t-2; c.cols[t]=88; }
        gemmk<5,0,1><<<dim3(128,2), 256, 0, stream>>>(c, wu, wu+SB3C, nullptr, 480,
            b3c, nullptr, nullptr, 1, wu+SX3, nullptr, nullptr, 88, 88);
    }
    {   // mp: cat @ WBMP + bmp + x -> MPb (bf16) + MP (fp32)
        GemmChunks c{};
        c.soff[0]=SXCAT; c.stride[0]=264; c.shift[0]=0; c.cols[0]=88;
        c.soff[1]=SX2;   c.stride[1]=88;  c.shift[1]=0; c.cols[1]=88;
        c.soff[2]=SX3;   c.stride[2]=88;  c.shift[2]=0; c.cols[2]=88;
        gemmk<3,0,3><<<dim3(128,2), 256, 0, stream>>>(c, wu, wu+SBMP, nullptr, 288,
            bmp, nullptr, x, 0, wu+SMPB, nullptr, ws+OFF_MP, 88, 88);
    }
    {   // qkv: MPb @ WBQKV -> Qb/Kb bf16 + V fp32
        GemmChunks c{}; c.soff[0]=SMPB; c.stride[0]=88; c.shift[0]=0; c.cols[0]=88;
        gemmk<1,1,0><<<dim3(128,6), 256, 0, stream>>>(c, wu, wu+SBQKV, nullptr, 96,
            nullptr, nullptr, nullptr, 0, wu, nullptr, ws, 0, 0);
    }
    dwtk<<<512, 256, 0, stream>>>(ws);
    attnk<<<dim3(32, 16), 512, 0, stream>>>(ws);
    {   // final: XOb @ WBOUT + bout + MP -> out
        GemmChunks c{};
        c.soff[0]=SXOB;    c.stride[0]=112; c.shift[0]=0; c.cols[0]=96;
        c.soff[1]=SXOB+96; c.stride[1]=112; c.shift[1]=0; c.cols[1]=16;
        gemmk<2,0,2><<<dim3(128,2), 256, 0, stream>>>(c, wu, wu+SBOUT, nullptr, 192,
            bout, nullptr, ws+OFF_MP, 0, nullptr, nullptr, out, 88, 88);
    }
}